// Round 17
// baseline (380.809 us; speedup 1.0000x reference)
//
#include <hip/hip_runtime.h>
#include <hip/hip_bf16.h>
#include <math.h>

#define Bn 2
#define Ln 4096
#define Dn 1024
#define Hn 4
#define DKn 256
#define DVn 256
#define NCHn 128  // L/32 chunks

typedef __attribute__((ext_vector_type(8))) short short8;
typedef __attribute__((ext_vector_type(4))) float f32x4;

__device__ __forceinline__ float sigmoidf_(float x) { return 1.f / (1.f + __expf(-x)); }

__device__ __forceinline__ unsigned short f2bf(float f) {
  union { float f; unsigned u; } v; v.f = f;
  unsigned r = v.u + 0x7FFFu + ((v.u >> 16) & 1u);
  return (unsigned short)(r >> 16);
}

__device__ __forceinline__ float bf2f(unsigned short u) {
  union { unsigned u; float f; } v; v.u = ((unsigned)u) << 16;
  return v.f;
}

__device__ __forceinline__ unsigned cvt_pk_bf16(float a, float b) {
  unsigned r;
  asm volatile("v_cvt_pk_bf16_f32 %0, %1, %2" : "=v"(r) : "v"(a), "v"(b));
  return r;
}

__device__ __forceinline__ short8 pack_i4(int4 o) {
  short8 r;
  __builtin_memcpy(&r, &o, 16);
  return r;
}

__device__ __forceinline__ void gl2lds16(const void* g, void* l) {
  __builtin_amdgcn_global_load_lds((const __attribute__((address_space(1))) unsigned int*)g,
                                   (__attribute__((address_space(3))) unsigned int*)l, 16, 0, 0);
}

// ---------------------------------------------------------------------------
// Batched weight transpose + bf16 convert: 4 weights in one launch (z axis).
// ---------------------------------------------------------------------------
__global__ __launch_bounds__(256) void wt_all_kernel(
    const float* __restrict__ W0, const float* __restrict__ W1,
    const float* __restrict__ W2, const float* __restrict__ W3,
    unsigned short* __restrict__ T0, unsigned short* __restrict__ T1,
    unsigned short* __restrict__ T2, unsigned short* __restrict__ T3) {
  const float* W = (blockIdx.z == 0) ? W0 : (blockIdx.z == 1) ? W1
                   : (blockIdx.z == 2) ? W2 : W3;
  unsigned short* Wt = (blockIdx.z == 0) ? T0 : (blockIdx.z == 1) ? T1
                       : (blockIdx.z == 2) ? T2 : T3;
  __shared__ float tile[32][33];
  const int bx = blockIdx.x * 32;  // n
  const int by = blockIdx.y * 32;  // k
  const int tx = threadIdx.x & 31, ty4 = (threadIdx.x >> 5) * 4;
#pragma unroll
  for (int r = 0; r < 4; ++r)
    tile[ty4 + r][tx] = W[(size_t)(by + ty4 + r) * 1024 + bx + tx];
  __syncthreads();
#pragma unroll
  for (int r = 0; r < 4; ++r)
    Wt[(size_t)(bx + ty4 + r) * 1024 + by + tx] = f2bf(tile[tx][ty4 + r]);
}

// ---------------------------------------------------------------------------
// bf16 MFMA GEMM: C = A @ Bt^T. 128x128 tile, BK=32. OBF: bf16 output.
// ---------------------------------------------------------------------------
template <int OBF>
__global__ __launch_bounds__(256, 2) void gemm_bf16(const unsigned short* __restrict__ A,
                                                    const unsigned short* __restrict__ Bt,
                                                    void* __restrict__ Cv,
                                                    int M, int N, int K) {
  __shared__ __align__(16) unsigned short As[128 * 32];
  __shared__ __align__(16) unsigned short Bs[128 * 32];
  const int tid = threadIdx.x;
  const int wid = tid >> 6, lane = tid & 63;
  const int row0 = blockIdx.y * 128, col0 = blockIdx.x * 128;
  const int wr64 = (wid >> 1) * 64, wc64 = (wid & 1) * 64;
  const int fr = lane & 15, fg = lane >> 4;
  f32x4 acc[4][4];
#pragma unroll
  for (int i = 0; i < 4; ++i)
#pragma unroll
    for (int j = 0; j < 4; ++j) acc[i][j] = (f32x4){0.f, 0.f, 0.f, 0.f};
  for (int k0 = 0; k0 < K; k0 += 32) {
#pragma unroll
    for (int i = 0; i < 2; ++i) {
      const int off = wid * 2048 + i * 1024 + (lane << 4);
      const int r = off >> 6;
      const int kb = off & 63;
      gl2lds16((const char*)A + ((size_t)(row0 + r) * K + k0) * 2 + kb, (char*)As + off);
      gl2lds16((const char*)Bt + ((size_t)(col0 + r) * K + k0) * 2 + kb, (char*)Bs + off);
    }
    __syncthreads();
    short8 a[4], b[4];
#pragma unroll
    for (int mi = 0; mi < 4; ++mi)
      a[mi] = *(const short8*)&As[(wr64 + mi * 16 + fr) * 32 + fg * 8];
#pragma unroll
    for (int ni = 0; ni < 4; ++ni)
      b[ni] = *(const short8*)&Bs[(wc64 + ni * 16 + fr) * 32 + fg * 8];
#pragma unroll
    for (int mi = 0; mi < 4; ++mi)
#pragma unroll
      for (int ni = 0; ni < 4; ++ni)
        acc[mi][ni] = __builtin_amdgcn_mfma_f32_16x16x32_bf16(a[mi], b[ni], acc[mi][ni], 0, 0, 0);
    __syncthreads();
  }
#pragma unroll
  for (int mi = 0; mi < 4; ++mi) {
    const int orow = row0 + wr64 + mi * 16 + fg * 4;
#pragma unroll
    for (int ni = 0; ni < 4; ++ni) {
      const int ocol = col0 + wc64 + ni * 16 + fr;
      if (OBF) {
        unsigned short* C = (unsigned short*)Cv;
#pragma unroll
        for (int r = 0; r < 4; ++r)
          C[(size_t)(orow + r) * N + ocol] = f2bf(acc[mi][ni][r]);
      } else {
        float* C = (float*)Cv;
#pragma unroll
        for (int r = 0; r < 4; ++r)
          C[(size_t)(orow + r) * N + ocol] = acc[mi][ni][r];
      }
    }
  }
}

// ---------------------------------------------------------------------------
// Gates + x->bf16 conversion (f2bf pass folded in).
// ---------------------------------------------------------------------------
__global__ __launch_bounds__(256) void gates_kernel(
    const float* __restrict__ x, const float* __restrict__ Wb,
    const float* __restrict__ Wg, const float* __restrict__ bg,
    const float* __restrict__ Wl, const float* __restrict__ bl,
    const float* __restrict__ log_temp, float* __restrict__ beta,
    float* __restrict__ wgl, float* __restrict__ pmix,
    unsigned short* __restrict__ xb) {
  const int wave = threadIdx.x >> 6, lane = threadIdx.x & 63;
  const int row = (blockIdx.x << 2) + wave;
  if (row >= Bn * Ln) return;
  const float* xr = x + (size_t)row * Dn;
  float acc[20];
#pragma unroll
  for (int c = 0; c < 20; ++c) acc[c] = 0.f;
#pragma unroll
  for (int i = 0; i < 4; ++i) {
    const float4 xv = *(const float4*)&xr[(lane << 2) + (i << 8)];
    ushort4 ob;
    ob.x = f2bf(xv.x); ob.y = f2bf(xv.y); ob.z = f2bf(xv.z); ob.w = f2bf(xv.w);
    *(ushort4*)&xb[(size_t)row * Dn + (i << 8) + (lane << 2)] = ob;
    const float xa[4] = {xv.x, xv.y, xv.z, xv.w};
#pragma unroll
    for (int j = 0; j < 4; ++j) {
      const int kk = (i << 8) + (lane << 2) + j;
      const float xx = xa[j];
#pragma unroll
      for (int h = 0; h < 4; ++h) acc[h] = fmaf(xx, Wb[kk * 4 + h], acc[h]);
#pragma unroll
      for (int h = 0; h < 4; ++h) acc[4 + h] = fmaf(xx, Wg[kk * 4 + h], acc[4 + h]);
#pragma unroll
      for (int c = 0; c < 12; ++c) acc[8 + c] = fmaf(xx, Wl[kk * 12 + c], acc[8 + c]);
    }
  }
#pragma unroll
  for (int c = 0; c < 20; ++c)
    for (int off = 32; off; off >>= 1) acc[c] += __shfl_down(acc[c], off);
  if (lane == 0) {
    const int b = row >> 12, l = row & (Ln - 1);
#pragma unroll
    for (int h = 0; h < 4; ++h)
      beta[((size_t)(b * Hn + h) << 12) + l] = sigmoidf_(acc[h]);
#pragma unroll
    for (int h = 0; h < 4; ++h) wgl[row * 4 + h] = sigmoidf_(acc[4 + h] + bg[h]);
#pragma unroll
    for (int h = 0; h < 4; ++h) {
      const float it = 1.f / __expf(log_temp[h]);
      const float l0 = (acc[8 + h * 3 + 0] + bl[h * 3 + 0]) * it;
      const float l1 = (acc[8 + h * 3 + 1] + bl[h * 3 + 1]) * it;
      const float l2 = (acc[8 + h * 3 + 2] + bl[h * 3 + 2]) * it;
      const float mx = fmaxf(l0, fmaxf(l1, l2));
      const float e0 = __expf(l0 - mx), e1 = __expf(l1 - mx), e2 = __expf(l2 - mx);
      const float is = 1.f / (e0 + e1 + e2);
      pmix[row * 12 + h * 3 + 0] = e0 * is;
      pmix[row * 12 + h * 3 + 1] = e1 * is;
      pmix[row * 12 + h * 3 + 2] = e2 * is;
    }
  }
}

// ---------------------------------------------------------------------------
// Conv v2 (round-16, passed): vectorized, barrier-free.
// ---------------------------------------------------------------------------
#define CLT 16
__global__ __launch_bounds__(384) void conv_fused_kernel(
    const unsigned short* __restrict__ qkv, const float* __restrict__ cq,
    const float* __restrict__ ck, const float* __restrict__ cv,
    unsigned short* __restrict__ qn, unsigned short* __restrict__ kn,
    unsigned short* __restrict__ vn) {
  const int wgid = ((int)blockIdx.x & 7) * 64 + ((int)blockIdx.x >> 3);
  const int b = wgid >> 8;
  const int lt = wgid & 255;
  const int l0 = lt * CLT;
  const int t = threadIdx.x;
  const int tensor = t >> 7;
  const int head = (t & 127) >> 5;
  const int ch0 = (t & 31) * 8;
  const int col = tensor * 1024 + head * 256 + ch0;
  const float* cw = (tensor == 0) ? cq : (tensor == 1) ? ck : cv;
  float w4[8][4];
#pragma unroll
  for (int e = 0; e < 8; ++e)
#pragma unroll
    for (int j = 0; j < 4; ++j) w4[e][j] = cw[(head * 256 + ch0 + e) * 4 + j];
  float h0[8], h1[8], h2[8];
#pragma unroll
  for (int e = 0; e < 8; ++e) { h0[e] = 0.f; h1[e] = 0.f; h2[e] = 0.f; }
  {
    if (l0 - 3 >= 0) {
      const short8 r = *(const short8*)&qkv[(((size_t)b << 12) + l0 - 3) * 3072 + col];
#pragma unroll
      for (int e = 0; e < 8; ++e) h0[e] = bf2f((unsigned short)r[e]);
    }
    if (l0 - 2 >= 0) {
      const short8 r = *(const short8*)&qkv[(((size_t)b << 12) + l0 - 2) * 3072 + col];
#pragma unroll
      for (int e = 0; e < 8; ++e) h1[e] = bf2f((unsigned short)r[e]);
    }
    if (l0 - 1 >= 0) {
      const short8 r = *(const short8*)&qkv[(((size_t)b << 12) + l0 - 1) * 3072 + col];
#pragma unroll
      for (int e = 0; e < 8; ++e) h2[e] = bf2f((unsigned short)r[e]);
    }
  }
  unsigned short* outp = (tensor == 0) ? qn : (tensor == 1) ? kn : vn;
  const size_t obase = (((size_t)(b * Hn + head)) << 12) * 256 + ch0;
#pragma unroll
  for (int i = 0; i < CLT; ++i) {
    const int l = l0 + i;
    const short8 r = *(const short8*)&qkv[(((size_t)b << 12) + l) * 3072 + col];
    float cur[8], a[8];
#pragma unroll
    for (int e = 0; e < 8; ++e) cur[e] = bf2f((unsigned short)r[e]);
    float ssq = 0.f;
#pragma unroll
    for (int e = 0; e < 8; ++e) {
      float s = w4[e][3] * cur[e];
      s = fmaf(w4[e][0], h0[e], s);
      s = fmaf(w4[e][1], h1[e], s);
      s = fmaf(w4[e][2], h2[e], s);
      const float y = s * sigmoidf_(s);
      a[e] = y;
      ssq = fmaf(y, y, ssq);
      h0[e] = h1[e]; h1[e] = h2[e]; h2[e] = cur[e];
    }
    float sc = 1.f;
    if (tensor < 2) {
#pragma unroll
      for (int m = 1; m <= 16; m <<= 1) ssq += __shfl_xor(ssq, m);
      sc = rsqrtf(ssq + 1e-6f);
    }
    short8 o;
#pragma unroll
    for (int e = 0; e < 8; ++e) o[e] = (short)f2bf(a[e] * sc);
    *(short8*)&outp[obase + (size_t)l * 256] = o;
  }
}

// ---------------------------------------------------------------------------
// Precomp v3 (round-16, passed).
// ---------------------------------------------------------------------------
__global__ __launch_bounds__(256, 2) void precomp_kernel(
    const unsigned short* __restrict__ q, const unsigned short* __restrict__ k,
    const unsigned short* __restrict__ v, const float* __restrict__ beta,
    unsigned short* __restrict__ wfrag, unsigned short* __restrict__ qfrag,
    unsigned short* __restrict__ ktfrag, unsigned short* __restrict__ afrag,
    float* __restrict__ u0frag) {
  const int blk = blockIdx.x;
  const int n = blk & 127, bh = blk >> 7;
  const size_t base = (((size_t)bh << 12) + (n << 5)) * 256;
  const size_t cid = (size_t)(bh * NCHn + n);
  __shared__ __align__(16) unsigned short ksb[32][264];
  __shared__ __align__(16) unsigned short qsb[32][264];
  __shared__ __align__(16) unsigned short vbb[32][264];
  __shared__ float Tm[32][33], Am[32][33], bet[32];
  __shared__ __align__(16) float attn_l[32][36];
  const int t = threadIdx.x;
  const int wid = t >> 6, lane = t & 63;
  const int fr = lane & 15, fg = lane >> 4;
  if (t < 32) bet[t] = beta[((size_t)bh << 12) + (n << 5) + t];
#pragma unroll
  for (int it = 0; it < 4; ++it) {
    const int idx = t + it * 256;
    const int r = idx >> 5, c8 = (idx & 31) << 3;
    const float bv = beta[((size_t)bh << 12) + (n << 5) + r];
    *(int4*)&qsb[r][c8] = *(const int4*)&q[base + r * 256 + c8];
    *(int4*)&ksb[r][c8] = *(const int4*)&k[base + r * 256 + c8];
    const int4 vv = *(const int4*)&v[base + r * 256 + c8];
    const unsigned vu[4] = {(unsigned)vv.x, (unsigned)vv.y, (unsigned)vv.z, (unsigned)vv.w};
    int4 ov;
    ov.x = cvt_pk_bf16(bf2f((unsigned short)(vu[0] & 0xffff)) * bv,
                       bf2f((unsigned short)(vu[0] >> 16)) * bv);
    ov.y = cvt_pk_bf16(bf2f((unsigned short)(vu[1] & 0xffff)) * bv,
                       bf2f((unsigned short)(vu[1] >> 16)) * bv);
    ov.z = cvt_pk_bf16(bf2f((unsigned short)(vu[2] & 0xffff)) * bv,
                       bf2f((unsigned short)(vu[2] >> 16)) * bv);
    ov.w = cvt_pk_bf16(bf2f((unsigned short)(vu[3] & 0xffff)) * bv,
                       bf2f((unsigned short)(vu[3] >> 16)) * bv);
    *(int4*)&vbb[r][c8] = ov;
  }
  __syncthreads();
  {
    const int ti = wid >> 1, tj = wid & 1;
    f32x4 G = (f32x4){0.f, 0.f, 0.f, 0.f};
    f32x4 At = (f32x4){0.f, 0.f, 0.f, 0.f};
#pragma unroll
    for (int kw = 0; kw < 8; ++kw) {
      const short8 krow = *(const short8*)&ksb[ti * 16 + fr][kw * 32 + fg * 8];
      const short8 kcol = *(const short8*)&ksb[tj * 16 + fr][kw * 32 + fg * 8];
      const short8 qrow = *(const short8*)&qsb[ti * 16 + fr][kw * 32 + fg * 8];
      G = __builtin_amdgcn_mfma_f32_16x16x32_bf16(krow, kcol, G, 0, 0, 0);
      At = __builtin_amdgcn_mfma_f32_16x16x32_bf16(qrow, kcol, At, 0, 0, 0);
    }
#pragma unroll
    for (int r_ = 0; r_ < 4; ++r_) {
      const int i = ti * 16 + fg * 4 + r_;
      const int j = tj * 16 + fr;
      Am[i][j] = bet[i] * G[r_];
      attn_l[i][j] = (j <= i) ? At[r_] : 0.f;
    }
  }
#pragma unroll
  for (int it = 0; it < 4; ++it) {
    const int u = it * 4 + wid;
    const int mi = u >> 3, kw = u & 7;
    *(int4*)&qfrag[cid * 8192 + u * 512 + lane * 8] =
        *(const int4*)&qsb[mi * 16 + fr][kw * 32 + fg * 8];
  }
#pragma unroll
  for (int it = 0; it < 4; ++it) {
    const int mi = it * 4 + wid;
    const int dk = mi * 16 + fr;
    unsigned short e[8];
#pragma unroll
    for (int j = 0; j < 8; ++j) e[j] = ksb[fg * 8 + j][dk];
    int4 o;
    o.x = e[0] | ((unsigned)e[1] << 16);
    o.y = e[2] | ((unsigned)e[3] << 16);
    o.z = e[4] | ((unsigned)e[5] << 16);
    o.w = e[6] | ((unsigned)e[7] << 16);
    *(int4*)&ktfrag[cid * 8192 + mi * 512 + lane * 8] = o;
  }
  __syncthreads();
  if (t >= 128) {
    const int mi = (t >> 6) - 2;
    const int c = mi * 16 + fr;
    const float4 a = *(const float4*)&attn_l[c][fg * 8];
    const float4 b2 = *(const float4*)&attn_l[c][fg * 8 + 4];
    int4 o;
    o.x = f2bf(a.x) | ((unsigned)f2bf(a.y) << 16);
    o.y = f2bf(a.z) | ((unsigned)f2bf(a.w) << 16);
    o.z = f2bf(b2.x) | ((unsigned)f2bf(b2.y) << 16);
    o.w = f2bf(b2.z) | ((unsigned)f2bf(b2.w) << 16);
    *(int4*)&afrag[cid * 1024 + mi * 512 + lane * 8] = o;
  }
  if (t < 32) {
    float Tcol[32];
    Tcol[0] = (t == 0) ? 1.f : 0.f;
#pragma unroll
    for (int i = 1; i < 32; ++i) {
      float s0 = 0.f, s1 = 0.f;
      int m = 0;
#pragma unroll
      for (; m + 2 <= i; m += 2) {
        s0 = fmaf(Am[i][m], Tcol[m], s0);
        s1 = fmaf(Am[i][m + 1], Tcol[m + 1], s1);
      }
      if (m < i) s0 = fmaf(Am[i][m], Tcol[m], s0);
      Tcol[i] = ((i == t) ? 1.f : 0.f) - s0 - s1;
    }
#pragma unroll
    for (int i = 0; i < 32; ++i) Tm[i][t] = Tcol[i];
  }
  __syncthreads();
  {
    float betr[8];
#pragma unroll
    for (int j = 0; j < 8; ++j) betr[j] = bet[fg * 8 + j];
    short8 Tf[2], Tbf[2];
#pragma unroll
    for (int mi = 0; mi < 2; ++mi) {
      float tv[8];
#pragma unroll
      for (int j = 0; j < 8; ++j) tv[j] = Tm[mi * 16 + fr][fg * 8 + j];
      int4 p, pb;
      p.x = cvt_pk_bf16(tv[0], tv[1]); p.y = cvt_pk_bf16(tv[2], tv[3]);
      p.z = cvt_pk_bf16(tv[4], tv[5]); p.w = cvt_pk_bf16(tv[6], tv[7]);
      pb.x = cvt_pk_bf16(tv[0] * betr[0], tv[1] * betr[1]);
      pb.y = cvt_pk_bf16(tv[2] * betr[2], tv[3] * betr[3]);
      pb.z = cvt_pk_bf16(tv[4] * betr[4], tv[5] * betr[5]);
      pb.w = cvt_pk_bf16(tv[6] * betr[6], tv[7] * betr[7]);
      Tf[mi] = pack_i4(p);
      Tbf[mi] = pack_i4(pb);
    }
    const f32x4 zero = (f32x4){0.f, 0.f, 0.f, 0.f};
#pragma unroll
    for (int tt = 0; tt < 4; ++tt) {
      const int tjc = wid * 4 + tt;
      unsigned short ev[8], ek[8];
#pragma unroll
      for (int j = 0; j < 8; ++j) {
        ev[j] = vbb[fg * 8 + j][tjc * 16 + fr];
        ek[j] = ksb[fg * 8 + j][tjc * 16 + fr];
      }
      int4 pv, pk;
      pv.x = ev[0] | ((unsigned)ev[1] << 16); pv.y = ev[2] | ((unsigned)ev[3] << 16);
      pv.z = ev[4] | ((unsigned)ev[5] << 16); pv.w = ev[6] | ((unsigned)ev[7] << 16);
      pk.x = ek[0] | ((unsigned)ek[1] << 16); pk.y = ek[2] | ((unsigned)ek[3] << 16);
      pk.z = ek[4] | ((unsigned)ek[5] << 16); pk.w = ek[6] | ((unsigned)ek[7] << 16);
      const short8 vbf = pack_i4(pv);
      const short8 kbf = pack_i4(pk);
#pragma unroll
      for (int mi = 0; mi < 2; ++mi) {
        const f32x4 U = __builtin_amdgcn_mfma_f32_16x16x32_bf16(Tf[mi], vbf, zero, 0, 0, 0);
        *(f32x4*)&u0frag[cid * 8192 + (tjc * 2 + mi) * 256 + lane * 4] = U;
        const f32x4 W = __builtin_amdgcn_mfma_f32_16x16x32_bf16(Tbf[mi], kbf, zero, 0, 0, 0);
#pragma unroll
        for (int r_ = 0; r_ < 4; ++r_)
          qsb[mi * 16 + fg * 4 + r_][tjc * 16 + fr] = f2bf(W[r_]);
      }
    }
  }
  __syncthreads();
#pragma unroll
  for (int it = 0; it < 4; ++it) {
    const int u = it * 4 + wid;
    const int mi = u >> 3, kw = u & 7;
    *(int4*)&wfrag[cid * 8192 + u * 512 + lane * 8] =
        *(const int4*)&qsb[mi * 16 + fr][kw * 32 + fg * 8];
  }
}

// ---------------------------------------------------------------------------
// Scan v8: 4 waves, dk split 4x64. Wave w owns dk [64w, 64w+64): S = 4 accs.
// Single barrier per chunk; u-combine sums 4 partials (pux[4][2][2][256]);
// each wave redundantly packs full ut into wave-private ut2[w].
// grid = 128 = 8 bh x 16 dv16, block = 256.
// ---------------------------------------------------------------------------
__global__ __launch_bounds__(256, 1) void scan_mfma(
    const unsigned short* __restrict__ wfrag, const unsigned short* __restrict__ qfrag,
    const unsigned short* __restrict__ ktfrag, const unsigned short* __restrict__ afrag,
    const float* __restrict__ u0frag, unsigned short* __restrict__ dout) {
  const int bh = blockIdx.x & 7;
  const int dvs = blockIdx.x >> 3;
  const int tid = threadIdx.x;
  const int w = tid >> 6;          // 0..3
  const int lane = tid & 63;
  const int fr = lane & 15, fg = lane >> 4;
  const int swz = (fr & 7) << 4;
  __shared__ __align__(16) unsigned short St[4][1024];   // per-wave [dv16][dk64]
  __shared__ __align__(16) unsigned short ut2[4][512];   // per-wave u bf16
  __shared__ __align__(16) float pux[4][2][2][256];      // [wave][buf][mi2]
  __shared__ __align__(16) float pox[4][2][2][256];
  f32x4 S[4];
#pragma unroll
  for (int i = 0; i < 4; ++i) S[i] = (f32x4){0.f, 0.f, 0.f, 0.f};

  const unsigned short* wbase = wfrag + (size_t)(bh * NCHn) * 8192;
  const unsigned short* qbase = qfrag + (size_t)(bh * NCHn) * 8192;
  const unsigned short* kbase = ktfrag + (size_t)(bh * NCHn) * 8192;
  const unsigned short* abase = afrag + (size_t)(bh * NCHn) * 1024;
  const float* ubase = u0frag + (size_t)(bh * NCHn) * 8192 + dvs * 512;

  short8 wr[2][2], qr[2][2], ktr[4];  // wr[mi2][kwp]; ktr[j] = dk tile 4w+j
  short8 ar[2] = {};
  f32x4 u0r[2];
#pragma unroll
  for (int mi2 = 0; mi2 < 2; ++mi2)
#pragma unroll
    for (int kwp = 0; kwp < 2; ++kwp) {
      const int u = mi2 * 8 + 2 * w + kwp;
      wr[mi2][kwp] = *(const short8*)&wbase[u * 512 + lane * 8];
      qr[mi2][kwp] = *(const short8*)&qbase[u * 512 + lane * 8];
    }
#pragma unroll
  for (int j = 0; j < 4; ++j)
    ktr[j] = *(const short8*)&kbase[(4 * w + j) * 512 + lane * 8];
#pragma unroll
  for (int u = 0; u < 2; ++u) u0r[u] = *(const f32x4*)&ubase[u * 256 + lane * 4];
  if (w == 0) {
#pragma unroll
    for (int u = 0; u < 2; ++u) ar[u] = *(const short8*)&abase[u * 512 + lane * 8];
  }

  for (int n = 0; n < NCHn; ++n) {
    const int np = (n + 1 < NCHn) ? (n + 1) : n;
    const int buf = n & 1;
    // pack S quarter -> St[w]  ([dv16][dk64], 128-byte rows, XOR swz)
#pragma unroll
    for (int j = 0; j < 4; ++j) {
      const unsigned w0 = cvt_pk_bf16(S[j][0], S[j][1]);
      const unsigned w1 = cvt_pk_bf16(S[j][2], S[j][3]);
      const int a = (fr * 128 + j * 32 + fg * 8) ^ swz;
      *(uint2*)((char*)&St[w][0] + a) = make_uint2(w0, w1);
    }
    short8 sb[2];
#pragma unroll
    for (int kwp = 0; kwp < 2; ++kwp) {
      const int a = (fr * 128 + kwp * 64 + fg * 16) ^ swz;
      sb[kwp] = *(const short8*)((const char*)&St[w][0] + a);
    }
    // partial w@S, q@S over own dk quarter (2-deep chains)
    f32x4 up[2], oq[2];
    up[0] = up[1] = (f32x4){0.f, 0.f, 0.f, 0.f};
    oq[0] = oq[1] = (f32x4){0.f, 0.f, 0.f, 0.f};
#pragma unroll
    for (int kwp = 0; kwp < 2; ++kwp) {
#pragma unroll
      for (int mi2 = 0; mi2 < 2; ++mi2) {
        up[mi2] = __builtin_amdgcn_mfma_f32_16x16x32_bf16(wr[mi2][kwp], sb[kwp], up[mi2], 0, 0, 0);
        oq[mi2] = __builtin_amdgcn_mfma_f32_16x16x32_bf16(qr[mi2][kwp], sb[kwp], oq[mi2], 0, 0, 0);
      }
    }
    // prefetch next chunk's w/q
    {
      const unsigned short* wp = wbase + (size_t)np * 8192;
      const unsigned short* qp = qbase + (size_t)np * 8192;
#pragma unroll
      for (int mi2 = 0; mi2 < 2; ++mi2)
#pragma unroll
        for (int kwp = 0; kwp < 2; ++kwp) {
          const int u = mi2 * 8 + 2 * w + kwp;
          wr[mi2][kwp] = *(const short8*)&wp[u * 512 + lane * 8];
          qr[mi2][kwp] = *(const short8*)&qp[u * 512 + lane * 8];
        }
    }
    // ship partials
#pragma unroll
    for (int mi2 = 0; mi2 < 2; ++mi2) {
      *(f32x4*)&pux[w][buf][mi2][lane * 4] = up[mi2];
      *(f32x4*)&pox[w][buf][mi2][lane * 4] = oq[mi2];
    }
    asm volatile("s_waitcnt lgkmcnt(0)" ::: "memory");
    __builtin_amdgcn_s_barrier();  // the ONE barrier: all partials visible
    __builtin_amdgcn_sched_barrier(0);
    // all waves: combine u (sum own + 3 others), pack own ut2
    f32x4 o_f[2];
#pragma unroll
    for (int mi2 = 0; mi2 < 2; ++mi2) {
      f32x4 s = up[mi2];
      s += *(const f32x4*)&pux[(w + 1) & 3][buf][mi2][lane * 4];
      s += *(const f32x4*)&pux[(w + 2) & 3][buf][mi2][lane * 4];
      s += *(const f32x4*)&pux[(w + 3) & 3][buf][mi2][lane * 4];
      const f32x4 uu = u0r[mi2] - s;
      const unsigned a0 = cvt_pk_bf16(uu[0], uu[1]);
      const unsigned a1 = cvt_pk_bf16(uu[2], uu[3]);
      const int ad = (fr * 64 + mi2 * 32 + fg * 8) ^ swz;
      *(uint2*)((char*)&ut2[w][0] + ad) = make_uint2(a0, a1);
      if (w == 0) {
        o_f[mi2] = oq[mi2];
        o_f[mi2] += *(const f32x4*)&pox[1][buf][mi2][lane * 4];
        o_f[mi2] += *(const f32x4*)&pox[2][buf][mi2][lane * 4];
        o_f[mi2] += *(const f32x4*)&pox[3][buf][mi2][lane * 4];
      }
    }
    asm volatile("s_waitcnt lgkmcnt(0)" ::: "memory");  // own ut2 writes drained
    __builtin_amdgcn_sched_barrier(0);
    const short8 ub = *(const short8*)((const char*)&ut2[w][0] + ((fr * 64 + fg * 16) ^ swz));
    if (w == 0) {
#pragma unroll
      for (int mi2 = 0; mi2 < 2; ++mi2)
        o_f[mi2] = __builtin_amdgcn_mfma_f32_16x16x32_bf16(ar[mi2], ub, o_f[mi2], 0, 0, 0);
      const unsigned short* ap = abase + (size_t)np * 1024;
#pragma unroll
      for (int u = 0; u < 2; ++u) ar[u] = *(const short8*)&ap[u * 512 + lane * 8];
      const size_t cb = ((size_t)((bh << 12) + (n << 5))) * 256;
#pragma unroll
      for (int mi2 = 0; mi2 < 2; ++mi2)
#pragma unroll
        for (int r = 0; r < 4; ++r)
          dout[cb + (size_t)(mi2 * 16 + fg * 4 + r) * 256 + dvs * 16 + fr] = f2bf(o_f[mi2][r]);
    }
    // prefetch u0r (all waves)
    {
      const float* up_ = ubase + (size_t)np * 8192;
#pragma unroll
      for (int u = 0; u < 2; ++u) u0r[u] = *(const f32x4*)&up_[u * 256 + lane * 4];
    }
    // S quarter += k^T @ u ; prefetch ktr
#pragma unroll
    for (int j = 0; j < 4; ++j)
      S[j] = __builtin_amdgcn_mfma_f32_16x16x32_bf16(ktr[j], ub, S[j], 0, 0, 0);
    {
      const unsigned short* kp = kbase + (size_t)np * 8192;
#pragma unroll
      for (int j = 0; j < 4; ++j)
        ktr[j] = *(const short8*)&kp[(4 * w + j) * 512 + lane * 8];
    }
  }
}

// ---------------------------------------------------------------------------
// Mix v4 (round-16, passed).
// ---------------------------------------------------------------------------
#define MIX_LT 16
__global__ __launch_bounds__(256) void mix_kernel(
    const unsigned short* __restrict__ v, const unsigned short* __restrict__ delta,
    const float* __restrict__ wgl, const float* __restrict__ pmix,
    const float* __restrict__ firs, const float* __restrict__ firl,
    const float* __restrict__ rms_w, unsigned short* __restrict__ out) {
  const int wgid = ((int)blockIdx.x & 7) * 256 + ((int)blockIdx.x >> 3);
  const int b = wgid >> 10;
  const int h = (wgid >> 8) & 3;
  const int lt = wgid & 255;
  const int l0 = lt * MIX_LT;
  const int t = threadIdx.x;
  const int wv = t >> 6, lane = t & 63;
  const unsigned short* vcol = v + ((((size_t)(b * Hn + h)) << 12)) * 256 + t;
  const unsigned short* dcol = delta + ((((size_t)(b * Hn + h)) << 12)) * 256 + t;
  float fw[31], fs3[3];
#pragma unroll
  for (int j = 0; j < 31; ++j) fw[j] = firl[((h << 8) + t) * 31 + j];
#pragma unroll
  for (int j = 0; j < 3; ++j) fs3[j] = firs[((h << 8) + t) * 3 + j];
  const float rw = rms_w[t];
  float vbuf[46];
#pragma unroll
  for (int j = 0; j < 30; ++j) {
    const int ls = l0 - 30 + j;
    vbuf[j] = (ls >= 0) ? bf2f(vcol[(size_t)ls * 256]) : 0.f;
  }
#pragma unroll
  for (int i = 0; i < MIX_LT; ++i) vbuf[30 + i] = bf2f(vcol[(size_t)(l0 + i) * 256]);
  __shared__ float wred[MIX_LT * 4];
  float o[MIX_LT];
#pragma unroll
  for (int i = 0; i < MIX_LT; ++i) {
    const int l = l0 + i;
    const float vnew = vbuf[30 + i];
    float lo = fw[30] * vnew;
#pragma unroll
    for (int j = 0; j < 30; ++j) lo = fmaf(fw[j], vbuf[i + j], lo);
    float sh = fs3[2] * vnew;
    sh = fmaf(fs3[1], vbuf[i + 29], sh);
    sh = fmaf(fs3[0], vbuf[i + 28], sh);
    const int row = (b << 12) + l;
    const float p0 = pmix[row * 12 + h * 3 + 0];
    const float p1 = pmix[row * 12 + h * 3 + 1];
    const float p2 = pmix[row * 12 + h * 3 + 2];
    const float wg = wgl[row * 4 + h];
    const float mixv = p0 * vnew + p1 * sh + p2 * lo;
    const float oo = wg * bf2f(dcol[(size_t)l * 256]) + (1.f - wg) * mixv;
    o[i] = oo;
    float ss = oo * oo;
#pragma unroll
    for (int m = 1; m < 64; m <<= 1) ss += __shfl_xor(ss, m);
    if (lane == 0) wred[i * 4 + wv] = ss;
  }
  __syncthreads();
#pragma unroll
  for (int i = 0; i < MIX_LT; ++i) {
    const float sum = wred[i * 4] + wred[i * 4 + 1] + wred[i * 4 + 2] + wred[i * 4 + 3];
    const float sc = rsqrtf(sum * (1.f / 256.f) + 1e-5f);
    const int l = l0 + i;
    out[(size_t)((b << 12) + l) * 1024 + (h << 8) + t] = f2bf(o[i] * sc * rw);
  }
}

// ---------------------------------------------------------------------------
extern "C" void kernel_launch(void* const* d_in, const int* in_sizes, int n_in,
                              void* d_out, int out_size, void* d_ws, size_t ws_size,
                              hipStream_t stream) {
  const float* x = (const float*)d_in[0];
  const float* Wq = (const float*)d_in[1];
  const float* Wk = (const float*)d_in[2];
  const float* Wv = (const float*)d_in[3];
  const float* cq = (const float*)d_in[4];
  const float* ck = (const float*)d_in[5];
  const float* cv = (const float*)d_in[6];
  const float* Wb = (const float*)d_in[7];
  const float* firs = (const float*)d_in[8];
  const float* firl = (const float*)d_in[9];
  const float* Wg = (const float*)d_in[10];
  const float* bg = (const float*)d_in[11];
  const float* Wl = (const float*)d_in[12];
  const float* bl = (const float*)d_in[13];
  const float* ltemp = (const float*)d_in[14];
  const float* rmsw = (const float*)d_in[15];
  const float* Wo = (const float*)d_in[16];

  float* ws = (float*)d_ws;
  const size_t NE = (size_t)Bn * Ln * 1024;  // 8.39M
  unsigned short* qkvbf = (unsigned short*)ws;
  unsigned short* wfrag = (unsigned short*)ws;
  unsigned short* qfrag = wfrag + 8388608;
  unsigned short* ktfrag = (unsigned short*)(ws + NE);
  unsigned short* afrag = ktfrag + 8388608;
  float* u0frag = ws + 2 * NE;
  unsigned short* xb = (unsigned short*)(ws + 3 * NE);
  unsigned short* normed_bf = xb;
  unsigned short* Wqt = xb + NE;
  unsigned short* Wkt = Wqt + 1048576;
  unsigned short* Wvt = Wkt + 1048576;
  unsigned short* qn_bf = (unsigned short*)(ws + 4 * NE);
  unsigned short* kn_bf = qn_bf + NE;
  unsigned short* vn_bf = (unsigned short*)(ws + 5 * NE);
  unsigned short* dout_bf = vn_bf + NE;
  float* beta = ws + 6 * NE;
  float* wgl = beta + (size_t)Bn * Hn * Ln;
  float* pmix = wgl + (size_t)Bn * Ln * Hn;
  unsigned short* Wot = (unsigned short*)(pmix + (size_t)Bn * Ln * Hn * 3);

  wt_all_kernel<<<dim3(32, 32, 4), 256, 0, stream>>>(Wq, Wk, Wv, Wo,
                                                     Wqt, Wkt, Wvt, Wot);
  gates_kernel<<<Bn * Ln / 4, 256, 0, stream>>>(x, Wb, Wg, bg, Wl, bl, ltemp,
                                                beta, wgl, pmix, xb);
  gemm_bf16<1><<<dim3(24, 64), 256, 0, stream>>>(xb, Wqt, qkvbf, Bn * Ln, 3072, 1024);
  conv_fused_kernel<<<Bn * (Ln / CLT), 384, 0, stream>>>(qkvbf, cq, ck, cv,
                                                         qn_bf, kn_bf, vn_bf);
  precomp_kernel<<<Bn * Hn * NCHn, 256, 0, stream>>>(qn_bf, kn_bf, vn_bf, beta,
                                                     wfrag, qfrag, ktfrag, afrag,
                                                     u0frag);
  scan_mfma<<<128, 256, 0, stream>>>(wfrag, qfrag, ktfrag, afrag, u0frag, dout_bf);
  mix_kernel<<<Bn * Hn * (Ln / MIX_LT), 256, 0, stream>>>(
      vn_bf, dout_bf, wgl, pmix, firs, firl, rmsw, normed_bf);
  gemm_bf16<0><<<dim3(8, 64), 256, 0, stream>>>(normed_bf, Wot, (float*)d_out,
                                                Bn * Ln, 1024, 1024);
}

// Round 18
// 370.893 us; speedup vs baseline: 1.0267x; 1.0267x over previous
//
#include <hip/hip_runtime.h>
#include <hip/hip_bf16.h>
#include <math.h>

#define Bn 2
#define Ln 4096
#define Dn 1024
#define Hn 4
#define DKn 256
#define DVn 256
#define NCHn 128  // L/32 chunks

typedef __attribute__((ext_vector_type(8))) short short8;
typedef __attribute__((ext_vector_type(4))) float f32x4;

__device__ __forceinline__ float sigmoidf_(float x) { return 1.f / (1.f + __expf(-x)); }

__device__ __forceinline__ unsigned short f2bf(float f) {
  union { float f; unsigned u; } v; v.f = f;
  unsigned r = v.u + 0x7FFFu + ((v.u >> 16) & 1u);
  return (unsigned short)(r >> 16);
}

__device__ __forceinline__ float bf2f(unsigned short u) {
  union { unsigned u; float f; } v; v.u = ((unsigned)u) << 16;
  return v.f;
}

__device__ __forceinline__ unsigned cvt_pk_bf16(float a, float b) {
  unsigned r;
  asm volatile("v_cvt_pk_bf16_f32 %0, %1, %2" : "=v"(r) : "v"(a), "v"(b));
  return r;
}

__device__ __forceinline__ short8 pack_i4(int4 o) {
  short8 r;
  __builtin_memcpy(&r, &o, 16);
  return r;
}

__device__ __forceinline__ void gl2lds16(const void* g, void* l) {
  __builtin_amdgcn_global_load_lds((const __attribute__((address_space(1))) unsigned int*)g,
                                   (__attribute__((address_space(3))) unsigned int*)l, 16, 0, 0);
}

// ---------------------------------------------------------------------------
// Batched weight transpose + bf16 convert: 4 weights in one launch (z axis).
// ---------------------------------------------------------------------------
__global__ __launch_bounds__(256) void wt_all_kernel(
    const float* __restrict__ W0, const float* __restrict__ W1,
    const float* __restrict__ W2, const float* __restrict__ W3,
    unsigned short* __restrict__ T0, unsigned short* __restrict__ T1,
    unsigned short* __restrict__ T2, unsigned short* __restrict__ T3) {
  const float* W = (blockIdx.z == 0) ? W0 : (blockIdx.z == 1) ? W1
                   : (blockIdx.z == 2) ? W2 : W3;
  unsigned short* Wt = (blockIdx.z == 0) ? T0 : (blockIdx.z == 1) ? T1
                       : (blockIdx.z == 2) ? T2 : T3;
  __shared__ float tile[32][33];
  const int bx = blockIdx.x * 32;  // n
  const int by = blockIdx.y * 32;  // k
  const int tx = threadIdx.x & 31, ty4 = (threadIdx.x >> 5) * 4;
#pragma unroll
  for (int r = 0; r < 4; ++r)
    tile[ty4 + r][tx] = W[(size_t)(by + ty4 + r) * 1024 + bx + tx];
  __syncthreads();
#pragma unroll
  for (int r = 0; r < 4; ++r)
    Wt[(size_t)(bx + ty4 + r) * 1024 + by + tx] = f2bf(tile[tx][ty4 + r]);
}

// ---------------------------------------------------------------------------
// bf16 MFMA GEMM: C = A @ Bt^T. 128x128 tile, BK=32. OBF: bf16 output.
// ---------------------------------------------------------------------------
template <int OBF>
__global__ __launch_bounds__(256, 2) void gemm_bf16(const unsigned short* __restrict__ A,
                                                    const unsigned short* __restrict__ Bt,
                                                    void* __restrict__ Cv,
                                                    int M, int N, int K) {
  __shared__ __align__(16) unsigned short As[128 * 32];
  __shared__ __align__(16) unsigned short Bs[128 * 32];
  const int tid = threadIdx.x;
  const int wid = tid >> 6, lane = tid & 63;
  const int row0 = blockIdx.y * 128, col0 = blockIdx.x * 128;
  const int wr64 = (wid >> 1) * 64, wc64 = (wid & 1) * 64;
  const int fr = lane & 15, fg = lane >> 4;
  f32x4 acc[4][4];
#pragma unroll
  for (int i = 0; i < 4; ++i)
#pragma unroll
    for (int j = 0; j < 4; ++j) acc[i][j] = (f32x4){0.f, 0.f, 0.f, 0.f};
  for (int k0 = 0; k0 < K; k0 += 32) {
#pragma unroll
    for (int i = 0; i < 2; ++i) {
      const int off = wid * 2048 + i * 1024 + (lane << 4);
      const int r = off >> 6;
      const int kb = off & 63;
      gl2lds16((const char*)A + ((size_t)(row0 + r) * K + k0) * 2 + kb, (char*)As + off);
      gl2lds16((const char*)Bt + ((size_t)(col0 + r) * K + k0) * 2 + kb, (char*)Bs + off);
    }
    __syncthreads();
    short8 a[4], b[4];
#pragma unroll
    for (int mi = 0; mi < 4; ++mi)
      a[mi] = *(const short8*)&As[(wr64 + mi * 16 + fr) * 32 + fg * 8];
#pragma unroll
    for (int ni = 0; ni < 4; ++ni)
      b[ni] = *(const short8*)&Bs[(wc64 + ni * 16 + fr) * 32 + fg * 8];
#pragma unroll
    for (int mi = 0; mi < 4; ++mi)
#pragma unroll
      for (int ni = 0; ni < 4; ++ni)
        acc[mi][ni] = __builtin_amdgcn_mfma_f32_16x16x32_bf16(a[mi], b[ni], acc[mi][ni], 0, 0, 0);
    __syncthreads();
  }
#pragma unroll
  for (int mi = 0; mi < 4; ++mi) {
    const int orow = row0 + wr64 + mi * 16 + fg * 4;
#pragma unroll
    for (int ni = 0; ni < 4; ++ni) {
      const int ocol = col0 + wc64 + ni * 16 + fr;
      if (OBF) {
        unsigned short* C = (unsigned short*)Cv;
#pragma unroll
        for (int r = 0; r < 4; ++r)
          C[(size_t)(orow + r) * N + ocol] = f2bf(acc[mi][ni][r]);
      } else {
        float* C = (float*)Cv;
#pragma unroll
        for (int r = 0; r < 4; ++r)
          C[(size_t)(orow + r) * N + ocol] = acc[mi][ni][r];
      }
    }
  }
}

// ---------------------------------------------------------------------------
// Gates + x->bf16 conversion (f2bf pass folded in).
// ---------------------------------------------------------------------------
__global__ __launch_bounds__(256) void gates_kernel(
    const float* __restrict__ x, const float* __restrict__ Wb,
    const float* __restrict__ Wg, const float* __restrict__ bg,
    const float* __restrict__ Wl, const float* __restrict__ bl,
    const float* __restrict__ log_temp, float* __restrict__ beta,
    float* __restrict__ wgl, float* __restrict__ pmix,
    unsigned short* __restrict__ xb) {
  const int wave = threadIdx.x >> 6, lane = threadIdx.x & 63;
  const int row = (blockIdx.x << 2) + wave;
  if (row >= Bn * Ln) return;
  const float* xr = x + (size_t)row * Dn;
  float acc[20];
#pragma unroll
  for (int c = 0; c < 20; ++c) acc[c] = 0.f;
#pragma unroll
  for (int i = 0; i < 4; ++i) {
    const float4 xv = *(const float4*)&xr[(lane << 2) + (i << 8)];
    ushort4 ob;
    ob.x = f2bf(xv.x); ob.y = f2bf(xv.y); ob.z = f2bf(xv.z); ob.w = f2bf(xv.w);
    *(ushort4*)&xb[(size_t)row * Dn + (i << 8) + (lane << 2)] = ob;
    const float xa[4] = {xv.x, xv.y, xv.z, xv.w};
#pragma unroll
    for (int j = 0; j < 4; ++j) {
      const int kk = (i << 8) + (lane << 2) + j;
      const float xx = xa[j];
#pragma unroll
      for (int h = 0; h < 4; ++h) acc[h] = fmaf(xx, Wb[kk * 4 + h], acc[h]);
#pragma unroll
      for (int h = 0; h < 4; ++h) acc[4 + h] = fmaf(xx, Wg[kk * 4 + h], acc[4 + h]);
#pragma unroll
      for (int c = 0; c < 12; ++c) acc[8 + c] = fmaf(xx, Wl[kk * 12 + c], acc[8 + c]);
    }
  }
#pragma unroll
  for (int c = 0; c < 20; ++c)
    for (int off = 32; off; off >>= 1) acc[c] += __shfl_down(acc[c], off);
  if (lane == 0) {
    const int b = row >> 12, l = row & (Ln - 1);
#pragma unroll
    for (int h = 0; h < 4; ++h)
      beta[((size_t)(b * Hn + h) << 12) + l] = sigmoidf_(acc[h]);
#pragma unroll
    for (int h = 0; h < 4; ++h) wgl[row * 4 + h] = sigmoidf_(acc[4 + h] + bg[h]);
#pragma unroll
    for (int h = 0; h < 4; ++h) {
      const float it = 1.f / __expf(log_temp[h]);
      const float l0 = (acc[8 + h * 3 + 0] + bl[h * 3 + 0]) * it;
      const float l1 = (acc[8 + h * 3 + 1] + bl[h * 3 + 1]) * it;
      const float l2 = (acc[8 + h * 3 + 2] + bl[h * 3 + 2]) * it;
      const float mx = fmaxf(l0, fmaxf(l1, l2));
      const float e0 = __expf(l0 - mx), e1 = __expf(l1 - mx), e2 = __expf(l2 - mx);
      const float is = 1.f / (e0 + e1 + e2);
      pmix[row * 12 + h * 3 + 0] = e0 * is;
      pmix[row * 12 + h * 3 + 1] = e1 * is;
      pmix[row * 12 + h * 3 + 2] = e2 * is;
    }
  }
}

// ---------------------------------------------------------------------------
// Conv v2b: vectorized, barrier-free; CLT=8, grid 1024 (4 blocks/CU).
// ---------------------------------------------------------------------------
#define CLT 8
__global__ __launch_bounds__(384) void conv_fused_kernel(
    const unsigned short* __restrict__ qkv, const float* __restrict__ cq,
    const float* __restrict__ ck, const float* __restrict__ cv,
    unsigned short* __restrict__ qn, unsigned short* __restrict__ kn,
    unsigned short* __restrict__ vn) {
  const int wgid = ((int)blockIdx.x & 7) * 128 + ((int)blockIdx.x >> 3);
  const int b = wgid >> 9;
  const int lt = wgid & 511;
  const int l0 = lt * CLT;
  const int t = threadIdx.x;
  const int tensor = t >> 7;
  const int head = (t & 127) >> 5;
  const int ch0 = (t & 31) * 8;
  const int col = tensor * 1024 + head * 256 + ch0;
  const float* cw = (tensor == 0) ? cq : (tensor == 1) ? ck : cv;
  float w4[8][4];
#pragma unroll
  for (int e = 0; e < 8; ++e)
#pragma unroll
    for (int j = 0; j < 4; ++j) w4[e][j] = cw[(head * 256 + ch0 + e) * 4 + j];
  float h0[8], h1[8], h2[8];
#pragma unroll
  for (int e = 0; e < 8; ++e) { h0[e] = 0.f; h1[e] = 0.f; h2[e] = 0.f; }
  {
    if (l0 - 3 >= 0) {
      const short8 r = *(const short8*)&qkv[(((size_t)b << 12) + l0 - 3) * 3072 + col];
#pragma unroll
      for (int e = 0; e < 8; ++e) h0[e] = bf2f((unsigned short)r[e]);
    }
    if (l0 - 2 >= 0) {
      const short8 r = *(const short8*)&qkv[(((size_t)b << 12) + l0 - 2) * 3072 + col];
#pragma unroll
      for (int e = 0; e < 8; ++e) h1[e] = bf2f((unsigned short)r[e]);
    }
    if (l0 - 1 >= 0) {
      const short8 r = *(const short8*)&qkv[(((size_t)b << 12) + l0 - 1) * 3072 + col];
#pragma unroll
      for (int e = 0; e < 8; ++e) h2[e] = bf2f((unsigned short)r[e]);
    }
  }
  unsigned short* outp = (tensor == 0) ? qn : (tensor == 1) ? kn : vn;
  const size_t obase = (((size_t)(b * Hn + head)) << 12) * 256 + ch0;
#pragma unroll
  for (int i = 0; i < CLT; ++i) {
    const int l = l0 + i;
    const short8 r = *(const short8*)&qkv[(((size_t)b << 12) + l) * 3072 + col];
    float cur[8], a[8];
#pragma unroll
    for (int e = 0; e < 8; ++e) cur[e] = bf2f((unsigned short)r[e]);
    float ssq = 0.f;
#pragma unroll
    for (int e = 0; e < 8; ++e) {
      float s = w4[e][3] * cur[e];
      s = fmaf(w4[e][0], h0[e], s);
      s = fmaf(w4[e][1], h1[e], s);
      s = fmaf(w4[e][2], h2[e], s);
      const float y = s * sigmoidf_(s);
      a[e] = y;
      ssq = fmaf(y, y, ssq);
      h0[e] = h1[e]; h1[e] = h2[e]; h2[e] = cur[e];
    }
    float sc = 1.f;
    if (tensor < 2) {
#pragma unroll
      for (int m = 1; m <= 16; m <<= 1) ssq += __shfl_xor(ssq, m);
      sc = rsqrtf(ssq + 1e-6f);
    }
    short8 o;
#pragma unroll
    for (int e = 0; e < 8; ++e) o[e] = (short)f2bf(a[e] * sc);
    *(short8*)&outp[obase + (size_t)l * 256] = o;
  }
}

// ---------------------------------------------------------------------------
// Precomp v3 (round-16, passed).
// ---------------------------------------------------------------------------
__global__ __launch_bounds__(256, 2) void precomp_kernel(
    const unsigned short* __restrict__ q, const unsigned short* __restrict__ k,
    const unsigned short* __restrict__ v, const float* __restrict__ beta,
    unsigned short* __restrict__ wfrag, unsigned short* __restrict__ qfrag,
    unsigned short* __restrict__ ktfrag, unsigned short* __restrict__ afrag,
    float* __restrict__ u0frag) {
  const int blk = blockIdx.x;
  const int n = blk & 127, bh = blk >> 7;
  const size_t base = (((size_t)bh << 12) + (n << 5)) * 256;
  const size_t cid = (size_t)(bh * NCHn + n);
  __shared__ __align__(16) unsigned short ksb[32][264];
  __shared__ __align__(16) unsigned short qsb[32][264];
  __shared__ __align__(16) unsigned short vbb[32][264];
  __shared__ float Tm[32][33], Am[32][33], bet[32];
  __shared__ __align__(16) float attn_l[32][36];
  const int t = threadIdx.x;
  const int wid = t >> 6, lane = t & 63;
  const int fr = lane & 15, fg = lane >> 4;
  if (t < 32) bet[t] = beta[((size_t)bh << 12) + (n << 5) + t];
#pragma unroll
  for (int it = 0; it < 4; ++it) {
    const int idx = t + it * 256;
    const int r = idx >> 5, c8 = (idx & 31) << 3;
    const float bv = beta[((size_t)bh << 12) + (n << 5) + r];
    *(int4*)&qsb[r][c8] = *(const int4*)&q[base + r * 256 + c8];
    *(int4*)&ksb[r][c8] = *(const int4*)&k[base + r * 256 + c8];
    const int4 vv = *(const int4*)&v[base + r * 256 + c8];
    const unsigned vu[4] = {(unsigned)vv.x, (unsigned)vv.y, (unsigned)vv.z, (unsigned)vv.w};
    int4 ov;
    ov.x = cvt_pk_bf16(bf2f((unsigned short)(vu[0] & 0xffff)) * bv,
                       bf2f((unsigned short)(vu[0] >> 16)) * bv);
    ov.y = cvt_pk_bf16(bf2f((unsigned short)(vu[1] & 0xffff)) * bv,
                       bf2f((unsigned short)(vu[1] >> 16)) * bv);
    ov.z = cvt_pk_bf16(bf2f((unsigned short)(vu[2] & 0xffff)) * bv,
                       bf2f((unsigned short)(vu[2] >> 16)) * bv);
    ov.w = cvt_pk_bf16(bf2f((unsigned short)(vu[3] & 0xffff)) * bv,
                       bf2f((unsigned short)(vu[3] >> 16)) * bv);
    *(int4*)&vbb[r][c8] = ov;
  }
  __syncthreads();
  {
    const int ti = wid >> 1, tj = wid & 1;
    f32x4 G = (f32x4){0.f, 0.f, 0.f, 0.f};
    f32x4 At = (f32x4){0.f, 0.f, 0.f, 0.f};
#pragma unroll
    for (int kw = 0; kw < 8; ++kw) {
      const short8 krow = *(const short8*)&ksb[ti * 16 + fr][kw * 32 + fg * 8];
      const short8 kcol = *(const short8*)&ksb[tj * 16 + fr][kw * 32 + fg * 8];
      const short8 qrow = *(const short8*)&qsb[ti * 16 + fr][kw * 32 + fg * 8];
      G = __builtin_amdgcn_mfma_f32_16x16x32_bf16(krow, kcol, G, 0, 0, 0);
      At = __builtin_amdgcn_mfma_f32_16x16x32_bf16(qrow, kcol, At, 0, 0, 0);
    }
#pragma unroll
    for (int r_ = 0; r_ < 4; ++r_) {
      const int i = ti * 16 + fg * 4 + r_;
      const int j = tj * 16 + fr;
      Am[i][j] = bet[i] * G[r_];
      attn_l[i][j] = (j <= i) ? At[r_] : 0.f;
    }
  }
#pragma unroll
  for (int it = 0; it < 4; ++it) {
    const int u = it * 4 + wid;
    const int mi = u >> 3, kw = u & 7;
    *(int4*)&qfrag[cid * 8192 + u * 512 + lane * 8] =
        *(const int4*)&qsb[mi * 16 + fr][kw * 32 + fg * 8];
  }
#pragma unroll
  for (int it = 0; it < 4; ++it) {
    const int mi = it * 4 + wid;
    const int dk = mi * 16 + fr;
    unsigned short e[8];
#pragma unroll
    for (int j = 0; j < 8; ++j) e[j] = ksb[fg * 8 + j][dk];
    int4 o;
    o.x = e[0] | ((unsigned)e[1] << 16);
    o.y = e[2] | ((unsigned)e[3] << 16);
    o.z = e[4] | ((unsigned)e[5] << 16);
    o.w = e[6] | ((unsigned)e[7] << 16);
    *(int4*)&ktfrag[cid * 8192 + mi * 512 + lane * 8] = o;
  }
  __syncthreads();
  if (t >= 128) {
    const int mi = (t >> 6) - 2;
    const int c = mi * 16 + fr;
    const float4 a = *(const float4*)&attn_l[c][fg * 8];
    const float4 b2 = *(const float4*)&attn_l[c][fg * 8 + 4];
    int4 o;
    o.x = f2bf(a.x) | ((unsigned)f2bf(a.y) << 16);
    o.y = f2bf(a.z) | ((unsigned)f2bf(a.w) << 16);
    o.z = f2bf(b2.x) | ((unsigned)f2bf(b2.y) << 16);
    o.w = f2bf(b2.z) | ((unsigned)f2bf(b2.w) << 16);
    *(int4*)&afrag[cid * 1024 + mi * 512 + lane * 8] = o;
  }
  if (t < 32) {
    float Tcol[32];
    Tcol[0] = (t == 0) ? 1.f : 0.f;
#pragma unroll
    for (int i = 1; i < 32; ++i) {
      float s0 = 0.f, s1 = 0.f;
      int m = 0;
#pragma unroll
      for (; m + 2 <= i; m += 2) {
        s0 = fmaf(Am[i][m], Tcol[m], s0);
        s1 = fmaf(Am[i][m + 1], Tcol[m + 1], s1);
      }
      if (m < i) s0 = fmaf(Am[i][m], Tcol[m], s0);
      Tcol[i] = ((i == t) ? 1.f : 0.f) - s0 - s1;
    }
#pragma unroll
    for (int i = 0; i < 32; ++i) Tm[i][t] = Tcol[i];
  }
  __syncthreads();
  {
    float betr[8];
#pragma unroll
    for (int j = 0; j < 8; ++j) betr[j] = bet[fg * 8 + j];
    short8 Tf[2], Tbf[2];
#pragma unroll
    for (int mi = 0; mi < 2; ++mi) {
      float tv[8];
#pragma unroll
      for (int j = 0; j < 8; ++j) tv[j] = Tm[mi * 16 + fr][fg * 8 + j];
      int4 p, pb;
      p.x = cvt_pk_bf16(tv[0], tv[1]); p.y = cvt_pk_bf16(tv[2], tv[3]);
      p.z = cvt_pk_bf16(tv[4], tv[5]); p.w = cvt_pk_bf16(tv[6], tv[7]);
      pb.x = cvt_pk_bf16(tv[0] * betr[0], tv[1] * betr[1]);
      pb.y = cvt_pk_bf16(tv[2] * betr[2], tv[3] * betr[3]);
      pb.z = cvt_pk_bf16(tv[4] * betr[4], tv[5] * betr[5]);
      pb.w = cvt_pk_bf16(tv[6] * betr[6], tv[7] * betr[7]);
      Tf[mi] = pack_i4(p);
      Tbf[mi] = pack_i4(pb);
    }
    const f32x4 zero = (f32x4){0.f, 0.f, 0.f, 0.f};
#pragma unroll
    for (int tt = 0; tt < 4; ++tt) {
      const int tjc = wid * 4 + tt;
      unsigned short ev[8], ek[8];
#pragma unroll
      for (int j = 0; j < 8; ++j) {
        ev[j] = vbb[fg * 8 + j][tjc * 16 + fr];
        ek[j] = ksb[fg * 8 + j][tjc * 16 + fr];
      }
      int4 pv, pk;
      pv.x = ev[0] | ((unsigned)ev[1] << 16); pv.y = ev[2] | ((unsigned)ev[3] << 16);
      pv.z = ev[4] | ((unsigned)ev[5] << 16); pv.w = ev[6] | ((unsigned)ev[7] << 16);
      pk.x = ek[0] | ((unsigned)ek[1] << 16); pk.y = ek[2] | ((unsigned)ek[3] << 16);
      pk.z = ek[4] | ((unsigned)ek[5] << 16); pk.w = ek[6] | ((unsigned)ek[7] << 16);
      const short8 vbf = pack_i4(pv);
      const short8 kbf = pack_i4(pk);
#pragma unroll
      for (int mi = 0; mi < 2; ++mi) {
        const f32x4 U = __builtin_amdgcn_mfma_f32_16x16x32_bf16(Tf[mi], vbf, zero, 0, 0, 0);
        *(f32x4*)&u0frag[cid * 8192 + (tjc * 2 + mi) * 256 + lane * 4] = U;
        const f32x4 W = __builtin_amdgcn_mfma_f32_16x16x32_bf16(Tbf[mi], kbf, zero, 0, 0, 0);
#pragma unroll
        for (int r_ = 0; r_ < 4; ++r_)
          qsb[mi * 16 + fg * 4 + r_][tjc * 16 + fr] = f2bf(W[r_]);
      }
    }
  }
  __syncthreads();
#pragma unroll
  for (int it = 0; it < 4; ++it) {
    const int u = it * 4 + wid;
    const int mi = u >> 3, kw = u & 7;
    *(int4*)&wfrag[cid * 8192 + u * 512 + lane * 8] =
        *(const int4*)&qsb[mi * 16 + fr][kw * 32 + fg * 8];
  }
}

// ---------------------------------------------------------------------------
// Scan v7b (round-16, passed): 2 waves, dk split 128/128, one barrier/chunk.
// ---------------------------------------------------------------------------
__global__ __launch_bounds__(128, 1) void scan_mfma(
    const unsigned short* __restrict__ wfrag, const unsigned short* __restrict__ qfrag,
    const unsigned short* __restrict__ ktfrag, const unsigned short* __restrict__ afrag,
    const float* __restrict__ u0frag, unsigned short* __restrict__ dout) {
  const int bh = blockIdx.x & 7;
  const int dvs = blockIdx.x >> 3;
  const int tid = threadIdx.x;
  const int w = tid >> 6;
  const int lane = tid & 63;
  const int fr = lane & 15, fg = lane >> 4;
  const int swz = (fr & 7) << 4;
  __shared__ __align__(16) unsigned short St[2][2048];
  __shared__ __align__(16) unsigned short ut2[2][512];
  __shared__ __align__(16) float pux[2][2][2][256];
  __shared__ __align__(16) float pox[2][2][2][256];
  f32x4 S[8];
#pragma unroll
  for (int i = 0; i < 8; ++i) S[i] = (f32x4){0.f, 0.f, 0.f, 0.f};

  const unsigned short* wbase = wfrag + (size_t)(bh * NCHn) * 8192;
  const unsigned short* qbase = qfrag + (size_t)(bh * NCHn) * 8192;
  const unsigned short* kbase = ktfrag + (size_t)(bh * NCHn) * 8192;
  const unsigned short* abase = afrag + (size_t)(bh * NCHn) * 1024;
  const float* ubase = u0frag + (size_t)(bh * NCHn) * 8192 + dvs * 512;

  short8 wr[8], qr[8], ktr[8];
  short8 ar[2] = {};
  f32x4 u0r[2];
#pragma unroll
  for (int u8 = 0; u8 < 8; ++u8) {
    const int mi = u8 >> 2, kwp = u8 & 3;
    const int u = mi * 8 + 4 * w + kwp;
    wr[u8] = *(const short8*)&wbase[u * 512 + lane * 8];
    qr[u8] = *(const short8*)&qbase[u * 512 + lane * 8];
    ktr[u8] = *(const short8*)&kbase[(8 * w + u8) * 512 + lane * 8];
  }
#pragma unroll
  for (int u = 0; u < 2; ++u) u0r[u] = *(const f32x4*)&ubase[u * 256 + lane * 4];
  if (w == 0) {
#pragma unroll
    for (int u = 0; u < 2; ++u) ar[u] = *(const short8*)&abase[u * 512 + lane * 8];
  }

  for (int n = 0; n < NCHn; ++n) {
    const int np = (n + 1 < NCHn) ? (n + 1) : n;
    const int buf = n & 1;
#pragma unroll
    for (int mi = 0; mi < 8; ++mi) {
      const unsigned w0 = cvt_pk_bf16(S[mi][0], S[mi][1]);
      const unsigned w1 = cvt_pk_bf16(S[mi][2], S[mi][3]);
      const int a = (fr * 256 + mi * 32 + fg * 8) ^ swz;
      *(uint2*)((char*)&St[w][0] + a) = make_uint2(w0, w1);
    }
    short8 sb[4];
#pragma unroll
    for (int kwp = 0; kwp < 4; ++kwp) {
      const int a = (fr * 256 + kwp * 64 + fg * 16) ^ swz;
      sb[kwp] = *(const short8*)((const char*)&St[w][0] + a);
    }
    f32x4 up[2], oq[2];
    up[0] = up[1] = (f32x4){0.f, 0.f, 0.f, 0.f};
    oq[0] = oq[1] = (f32x4){0.f, 0.f, 0.f, 0.f};
#pragma unroll
    for (int kwp = 0; kwp < 4; ++kwp) {
#pragma unroll
      for (int mi = 0; mi < 2; ++mi) {
        up[mi] = __builtin_amdgcn_mfma_f32_16x16x32_bf16(wr[mi * 4 + kwp], sb[kwp], up[mi], 0, 0, 0);
        oq[mi] = __builtin_amdgcn_mfma_f32_16x16x32_bf16(qr[mi * 4 + kwp], sb[kwp], oq[mi], 0, 0, 0);
      }
    }
    {
      const unsigned short* wp = wbase + (size_t)np * 8192;
      const unsigned short* qp = qbase + (size_t)np * 8192;
#pragma unroll
      for (int u8 = 0; u8 < 8; ++u8) {
        const int mi = u8 >> 2, kwp = u8 & 3;
        const int u = mi * 8 + 4 * w + kwp;
        wr[u8] = *(const short8*)&wp[u * 512 + lane * 8];
        qr[u8] = *(const short8*)&qp[u * 512 + lane * 8];
      }
    }
#pragma unroll
    for (int mi = 0; mi < 2; ++mi) {
      *(f32x4*)&pux[w][buf][mi][lane * 4] = up[mi];
      *(f32x4*)&pox[w][buf][mi][lane * 4] = oq[mi];
    }
    asm volatile("s_waitcnt lgkmcnt(0)" ::: "memory");
    __builtin_amdgcn_s_barrier();
    __builtin_amdgcn_sched_barrier(0);
    f32x4 o_f[2];
#pragma unroll
    for (int mi = 0; mi < 2; ++mi) {
      const f32x4 puo = *(const f32x4*)&pux[w ^ 1][buf][mi][lane * 4];
      const f32x4 uu = u0r[mi] - up[mi] - puo;
      const unsigned a0 = cvt_pk_bf16(uu[0], uu[1]);
      const unsigned a1 = cvt_pk_bf16(uu[2], uu[3]);
      const int ad = (fr * 64 + mi * 32 + fg * 8) ^ swz;
      *(uint2*)((char*)&ut2[w][0] + ad) = make_uint2(a0, a1);
      o_f[mi] = oq[mi] + *(const f32x4*)&pox[w ^ 1][buf][mi][lane * 4];
    }
    asm volatile("s_waitcnt lgkmcnt(0)" ::: "memory");
    __builtin_amdgcn_sched_barrier(0);
    const short8 ub = *(const short8*)((const char*)&ut2[w][0] + ((fr * 64 + fg * 16) ^ swz));
    if (w == 0) {
#pragma unroll
      for (int mi = 0; mi < 2; ++mi)
        o_f[mi] = __builtin_amdgcn_mfma_f32_16x16x32_bf16(ar[mi], ub, o_f[mi], 0, 0, 0);
      const unsigned short* ap = abase + (size_t)np * 1024;
#pragma unroll
      for (int u = 0; u < 2; ++u) ar[u] = *(const short8*)&ap[u * 512 + lane * 8];
      const size_t cb = ((size_t)((bh << 12) + (n << 5))) * 256;
#pragma unroll
      for (int mi = 0; mi < 2; ++mi)
#pragma unroll
        for (int r = 0; r < 4; ++r)
          dout[cb + (size_t)(mi * 16 + fg * 4 + r) * 256 + dvs * 16 + fr] = f2bf(o_f[mi][r]);
    }
    {
      const float* up_ = ubase + (size_t)np * 8192;
#pragma unroll
      for (int u = 0; u < 2; ++u) u0r[u] = *(const f32x4*)&up_[u * 256 + lane * 4];
    }
#pragma unroll
    for (int mi = 0; mi < 8; ++mi)
      S[mi] = __builtin_amdgcn_mfma_f32_16x16x32_bf16(ktr[mi], ub, S[mi], 0, 0, 0);
    {
      const unsigned short* kp = kbase + (size_t)np * 8192;
#pragma unroll
      for (int u8 = 0; u8 < 8; ++u8)
        ktr[u8] = *(const short8*)&kp[(8 * w + u8) * 512 + lane * 8];
    }
  }
}

// ---------------------------------------------------------------------------
// Mix v4 (round-16, passed).
// ---------------------------------------------------------------------------
#define MIX_LT 16
__global__ __launch_bounds__(256) void mix_kernel(
    const unsigned short* __restrict__ v, const unsigned short* __restrict__ delta,
    const float* __restrict__ wgl, const float* __restrict__ pmix,
    const float* __restrict__ firs, const float* __restrict__ firl,
    const float* __restrict__ rms_w, unsigned short* __restrict__ out) {
  const int wgid = ((int)blockIdx.x & 7) * 256 + ((int)blockIdx.x >> 3);
  const int b = wgid >> 10;
  const int h = (wgid >> 8) & 3;
  const int lt = wgid & 255;
  const int l0 = lt * MIX_LT;
  const int t = threadIdx.x;
  const int wv = t >> 6, lane = t & 63;
  const unsigned short* vcol = v + ((((size_t)(b * Hn + h)) << 12)) * 256 + t;
  const unsigned short* dcol = delta + ((((size_t)(b * Hn + h)) << 12)) * 256 + t;
  float fw[31], fs3[3];
#pragma unroll
  for (int j = 0; j < 31; ++j) fw[j] = firl[((h << 8) + t) * 31 + j];
#pragma unroll
  for (int j = 0; j < 3; ++j) fs3[j] = firs[((h << 8) + t) * 3 + j];
  const float rw = rms_w[t];
  float vbuf[46];
#pragma unroll
  for (int j = 0; j < 30; ++j) {
    const int ls = l0 - 30 + j;
    vbuf[j] = (ls >= 0) ? bf2f(vcol[(size_t)ls * 256]) : 0.f;
  }
#pragma unroll
  for (int i = 0; i < MIX_LT; ++i) vbuf[30 + i] = bf2f(vcol[(size_t)(l0 + i) * 256]);
  __shared__ float wred[MIX_LT * 4];
  float o[MIX_LT];
#pragma unroll
  for (int i = 0; i < MIX_LT; ++i) {
    const int l = l0 + i;
    const float vnew = vbuf[30 + i];
    float lo = fw[30] * vnew;
#pragma unroll
    for (int j = 0; j < 30; ++j) lo = fmaf(fw[j], vbuf[i + j], lo);
    float sh = fs3[2] * vnew;
    sh = fmaf(fs3[1], vbuf[i + 29], sh);
    sh = fmaf(fs3[0], vbuf[i + 28], sh);
    const int row = (b << 12) + l;
    const float p0 = pmix[row * 12 + h * 3 + 0];
    const float p1 = pmix[row * 12 + h * 3 + 1];
    const float p2 = pmix[row * 12 + h * 3 + 2];
    const float wg = wgl[row * 4 + h];
    const float mixv = p0 * vnew + p1 * sh + p2 * lo;
    const float oo = wg * bf2f(dcol[(size_t)l * 256]) + (1.f - wg) * mixv;
    o[i] = oo;
    float ss = oo * oo;
#pragma unroll
    for (int m = 1; m < 64; m <<= 1) ss += __shfl_xor(ss, m);
    if (lane == 0) wred[i * 4 + wv] = ss;
  }
  __syncthreads();
#pragma unroll
  for (int i = 0; i < MIX_LT; ++i) {
    const float sum = wred[i * 4] + wred[i * 4 + 1] + wred[i * 4 + 2] + wred[i * 4 + 3];
    const float sc = rsqrtf(sum * (1.f / 256.f) + 1e-5f);
    const int l = l0 + i;
    out[(size_t)((b << 12) + l) * 1024 + (h << 8) + t] = f2bf(o[i] * sc * rw);
  }
}

// ---------------------------------------------------------------------------
extern "C" void kernel_launch(void* const* d_in, const int* in_sizes, int n_in,
                              void* d_out, int out_size, void* d_ws, size_t ws_size,
                              hipStream_t stream) {
  const float* x = (const float*)d_in[0];
  const float* Wq = (const float*)d_in[1];
  const float* Wk = (const float*)d_in[2];
  const float* Wv = (const float*)d_in[3];
  const float* cq = (const float*)d_in[4];
  const float* ck = (const float*)d_in[5];
  const float* cv = (const float*)d_in[6];
  const float* Wb = (const float*)d_in[7];
  const float* firs = (const float*)d_in[8];
  const float* firl = (const float*)d_in[9];
  const float* Wg = (const float*)d_in[10];
  const float* bg = (const float*)d_in[11];
  const float* Wl = (const float*)d_in[12];
  const float* bl = (const float*)d_in[13];
  const float* ltemp = (const float*)d_in[14];
  const float* rmsw = (const float*)d_in[15];
  const float* Wo = (const float*)d_in[16];

  float* ws = (float*)d_ws;
  const size_t NE = (size_t)Bn * Ln * 1024;  // 8.39M
  unsigned short* qkvbf = (unsigned short*)ws;
  unsigned short* wfrag = (unsigned short*)ws;
  unsigned short* qfrag = wfrag + 8388608;
  unsigned short* ktfrag = (unsigned short*)(ws + NE);
  unsigned short* afrag = ktfrag + 8388608;
  float* u0frag = ws + 2 * NE;
  unsigned short* xb = (unsigned short*)(ws + 3 * NE);
  unsigned short* normed_bf = xb;
  unsigned short* Wqt = xb + NE;
  unsigned short* Wkt = Wqt + 1048576;
  unsigned short* Wvt = Wkt + 1048576;
  unsigned short* qn_bf = (unsigned short*)(ws + 4 * NE);
  unsigned short* kn_bf = qn_bf + NE;
  unsigned short* vn_bf = (unsigned short*)(ws + 5 * NE);
  unsigned short* dout_bf = vn_bf + NE;
  float* beta = ws + 6 * NE;
  float* wgl = beta + (size_t)Bn * Hn * Ln;
  float* pmix = wgl + (size_t)Bn * Ln * Hn;
  unsigned short* Wot = (unsigned short*)(pmix + (size_t)Bn * Ln * Hn * 3);

  wt_all_kernel<<<dim3(32, 32, 4), 256, 0, stream>>>(Wq, Wk, Wv, Wo,
                                                     Wqt, Wkt, Wvt, Wot);
  gates_kernel<<<Bn * Ln / 4, 256, 0, stream>>>(x, Wb, Wg, bg, Wl, bl, ltemp,
                                                beta, wgl, pmix, xb);
  gemm_bf16<1><<<dim3(24, 64), 256, 0, stream>>>(xb, Wqt, qkvbf, Bn * Ln, 3072, 1024);
  conv_fused_kernel<<<Bn * (Ln / CLT), 384, 0, stream>>>(qkvbf, cq, ck, cv,
                                                         qn_bf, kn_bf, vn_bf);
  precomp_kernel<<<Bn * Hn * NCHn, 256, 0, stream>>>(qn_bf, kn_bf, vn_bf, beta,
                                                     wfrag, qfrag, ktfrag, afrag,
                                                     u0frag);
  scan_mfma<<<128, 128, 0, stream>>>(wfrag, qfrag, ktfrag, afrag, u0frag, dout_bf);
  mix_kernel<<<Bn * Hn * (Ln / MIX_LT), 256, 0, stream>>>(
      vn_bf, dout_bf, wgl, pmix, firs, firl, rmsw, normed_bf);
  gemm_bf16<0><<<dim3(8, 64), 256, 0, stream>>>(normed_bf, Wot, (float*)d_out,
                                                Bn * Ln, 1024, 1024);
}

// Round 19
// 366.421 us; speedup vs baseline: 1.0393x; 1.0122x over previous
//
#include <hip/hip_runtime.h>
#include <hip/hip_bf16.h>
#include <math.h>

#define Bn 2
#define Ln 4096
#define Dn 1024
#define Hn 4
#define DKn 256
#define DVn 256
#define NCHn 128  // L/32 chunks

typedef __attribute__((ext_vector_type(8))) short short8;
typedef __attribute__((ext_vector_type(4))) float f32x4;

__device__ __forceinline__ float sigmoidf_(float x) { return 1.f / (1.f + __expf(-x)); }

__device__ __forceinline__ unsigned short f2bf(float f) {
  union { float f; unsigned u; } v; v.f = f;
  unsigned r = v.u + 0x7FFFu + ((v.u >> 16) & 1u);
  return (unsigned short)(r >> 16);
}

__device__ __forceinline__ float bf2f(unsigned short u) {
  union { unsigned u; float f; } v; v.u = ((unsigned)u) << 16;
  return v.f;
}

__device__ __forceinline__ unsigned cvt_pk_bf16(float a, float b) {
  unsigned r;
  asm volatile("v_cvt_pk_bf16_f32 %0, %1, %2" : "=v"(r) : "v"(a), "v"(b));
  return r;
}

__device__ __forceinline__ short8 pack_i4(int4 o) {
  short8 r;
  __builtin_memcpy(&r, &o, 16);
  return r;
}

__device__ __forceinline__ void gl2lds16(const void* g, void* l) {
  __builtin_amdgcn_global_load_lds((const __attribute__((address_space(1))) unsigned int*)g,
                                   (__attribute__((address_space(3))) unsigned int*)l, 16, 0, 0);
}

// ---------------------------------------------------------------------------
// Batched weight transpose + bf16 convert: 4 weights in one launch (z axis).
// ---------------------------------------------------------------------------
__global__ __launch_bounds__(256) void wt_all_kernel(
    const float* __restrict__ W0, const float* __restrict__ W1,
    const float* __restrict__ W2, const float* __restrict__ W3,
    unsigned short* __restrict__ T0, unsigned short* __restrict__ T1,
    unsigned short* __restrict__ T2, unsigned short* __restrict__ T3) {
  const float* W = (blockIdx.z == 0) ? W0 : (blockIdx.z == 1) ? W1
                   : (blockIdx.z == 2) ? W2 : W3;
  unsigned short* Wt = (blockIdx.z == 0) ? T0 : (blockIdx.z == 1) ? T1
                       : (blockIdx.z == 2) ? T2 : T3;
  __shared__ float tile[32][33];
  const int bx = blockIdx.x * 32;  // n
  const int by = blockIdx.y * 32;  // k
  const int tx = threadIdx.x & 31, ty4 = (threadIdx.x >> 5) * 4;
#pragma unroll
  for (int r = 0; r < 4; ++r)
    tile[ty4 + r][tx] = W[(size_t)(by + ty4 + r) * 1024 + bx + tx];
  __syncthreads();
#pragma unroll
  for (int r = 0; r < 4; ++r)
    Wt[(size_t)(bx + ty4 + r) * 1024 + by + tx] = f2bf(tile[tx][ty4 + r]);
}

// ---------------------------------------------------------------------------
// bf16 MFMA GEMM: C = A @ Bt^T. 128x128 tile, BK=32. OBF: bf16 output.
// 1D grid, XCD-bijective swizzle (nwg % 8 == 0).
// ---------------------------------------------------------------------------
template <int OBF>
__global__ __launch_bounds__(256, 2) void gemm_bf16(const unsigned short* __restrict__ A,
                                                    const unsigned short* __restrict__ Bt,
                                                    void* __restrict__ Cv,
                                                    int M, int N, int K) {
  __shared__ __align__(16) unsigned short As[128 * 32];
  __shared__ __align__(16) unsigned short Bs[128 * 32];
  const int tid = threadIdx.x;
  const int wid = tid >> 6, lane = tid & 63;
  const int gx = N >> 7;
  const int nwg = (int)gridDim.x;
  const int bid = (int)blockIdx.x;
  const int sw = ((bid & 7) * (nwg >> 3)) + (bid >> 3);  // bijective: nwg%8==0
  const int row0 = (sw / gx) * 128, col0 = (sw % gx) * 128;
  const int wr64 = (wid >> 1) * 64, wc64 = (wid & 1) * 64;
  const int fr = lane & 15, fg = lane >> 4;
  f32x4 acc[4][4];
#pragma unroll
  for (int i = 0; i < 4; ++i)
#pragma unroll
    for (int j = 0; j < 4; ++j) acc[i][j] = (f32x4){0.f, 0.f, 0.f, 0.f};
  for (int k0 = 0; k0 < K; k0 += 32) {
#pragma unroll
    for (int i = 0; i < 2; ++i) {
      const int off = wid * 2048 + i * 1024 + (lane << 4);
      const int r = off >> 6;
      const int kb = off & 63;
      gl2lds16((const char*)A + ((size_t)(row0 + r) * K + k0) * 2 + kb, (char*)As + off);
      gl2lds16((const char*)Bt + ((size_t)(col0 + r) * K + k0) * 2 + kb, (char*)Bs + off);
    }
    __syncthreads();
    short8 a[4], b[4];
#pragma unroll
    for (int mi = 0; mi < 4; ++mi)
      a[mi] = *(const short8*)&As[(wr64 + mi * 16 + fr) * 32 + fg * 8];
#pragma unroll
    for (int ni = 0; ni < 4; ++ni)
      b[ni] = *(const short8*)&Bs[(wc64 + ni * 16 + fr) * 32 + fg * 8];
#pragma unroll
    for (int mi = 0; mi < 4; ++mi)
#pragma unroll
      for (int ni = 0; ni < 4; ++ni)
        acc[mi][ni] = __builtin_amdgcn_mfma_f32_16x16x32_bf16(a[mi], b[ni], acc[mi][ni], 0, 0, 0);
    __syncthreads();
  }
#pragma unroll
  for (int mi = 0; mi < 4; ++mi) {
    const int orow = row0 + wr64 + mi * 16 + fg * 4;
#pragma unroll
    for (int ni = 0; ni < 4; ++ni) {
      const int ocol = col0 + wc64 + ni * 16 + fr;
      if (OBF) {
        unsigned short* C = (unsigned short*)Cv;
#pragma unroll
        for (int r = 0; r < 4; ++r)
          C[(size_t)(orow + r) * N + ocol] = f2bf(acc[mi][ni][r]);
      } else {
        float* C = (float*)Cv;
#pragma unroll
        for (int r = 0; r < 4; ++r)
          C[(size_t)(orow + r) * N + ocol] = acc[mi][ni][r];
      }
    }
  }
}

// ---------------------------------------------------------------------------
// Gates + x->bf16 conversion (f2bf pass folded in).
// ---------------------------------------------------------------------------
__global__ __launch_bounds__(256) void gates_kernel(
    const float* __restrict__ x, const float* __restrict__ Wb,
    const float* __restrict__ Wg, const float* __restrict__ bg,
    const float* __restrict__ Wl, const float* __restrict__ bl,
    const float* __restrict__ log_temp, float* __restrict__ beta,
    float* __restrict__ wgl, float* __restrict__ pmix,
    unsigned short* __restrict__ xb) {
  const int wave = threadIdx.x >> 6, lane = threadIdx.x & 63;
  const int row = (blockIdx.x << 2) + wave;
  if (row >= Bn * Ln) return;
  const float* xr = x + (size_t)row * Dn;
  float acc[20];
#pragma unroll
  for (int c = 0; c < 20; ++c) acc[c] = 0.f;
#pragma unroll
  for (int i = 0; i < 4; ++i) {
    const float4 xv = *(const float4*)&xr[(lane << 2) + (i << 8)];
    ushort4 ob;
    ob.x = f2bf(xv.x); ob.y = f2bf(xv.y); ob.z = f2bf(xv.z); ob.w = f2bf(xv.w);
    *(ushort4*)&xb[(size_t)row * Dn + (i << 8) + (lane << 2)] = ob;
    const float xa[4] = {xv.x, xv.y, xv.z, xv.w};
#pragma unroll
    for (int j = 0; j < 4; ++j) {
      const int kk = (i << 8) + (lane << 2) + j;
      const float xx = xa[j];
#pragma unroll
      for (int h = 0; h < 4; ++h) acc[h] = fmaf(xx, Wb[kk * 4 + h], acc[h]);
#pragma unroll
      for (int h = 0; h < 4; ++h) acc[4 + h] = fmaf(xx, Wg[kk * 4 + h], acc[4 + h]);
#pragma unroll
      for (int c = 0; c < 12; ++c) acc[8 + c] = fmaf(xx, Wl[kk * 12 + c], acc[8 + c]);
    }
  }
#pragma unroll
  for (int c = 0; c < 20; ++c)
    for (int off = 32; off; off >>= 1) acc[c] += __shfl_down(acc[c], off);
  if (lane == 0) {
    const int b = row >> 12, l = row & (Ln - 1);
#pragma unroll
    for (int h = 0; h < 4; ++h)
      beta[((size_t)(b * Hn + h) << 12) + l] = sigmoidf_(acc[h]);
#pragma unroll
    for (int h = 0; h < 4; ++h) wgl[row * 4 + h] = sigmoidf_(acc[4 + h] + bg[h]);
#pragma unroll
    for (int h = 0; h < 4; ++h) {
      const float it = 1.f / __expf(log_temp[h]);
      const float l0 = (acc[8 + h * 3 + 0] + bl[h * 3 + 0]) * it;
      const float l1 = (acc[8 + h * 3 + 1] + bl[h * 3 + 1]) * it;
      const float l2 = (acc[8 + h * 3 + 2] + bl[h * 3 + 2]) * it;
      const float mx = fmaxf(l0, fmaxf(l1, l2));
      const float e0 = __expf(l0 - mx), e1 = __expf(l1 - mx), e2 = __expf(l2 - mx);
      const float is = 1.f / (e0 + e1 + e2);
      pmix[row * 12 + h * 3 + 0] = e0 * is;
      pmix[row * 12 + h * 3 + 1] = e1 * is;
      pmix[row * 12 + h * 3 + 2] = e2 * is;
    }
  }
}

// ---------------------------------------------------------------------------
// Conv v2b (round-18, passed): vectorized, barrier-free; CLT=8, grid 1024.
// ---------------------------------------------------------------------------
#define CLT 8
__global__ __launch_bounds__(384) void conv_fused_kernel(
    const unsigned short* __restrict__ qkv, const float* __restrict__ cq,
    const float* __restrict__ ck, const float* __restrict__ cv,
    unsigned short* __restrict__ qn, unsigned short* __restrict__ kn,
    unsigned short* __restrict__ vn) {
  const int wgid = ((int)blockIdx.x & 7) * 128 + ((int)blockIdx.x >> 3);
  const int b = wgid >> 9;
  const int lt = wgid & 511;
  const int l0 = lt * CLT;
  const int t = threadIdx.x;
  const int tensor = t >> 7;
  const int head = (t & 127) >> 5;
  const int ch0 = (t & 31) * 8;
  const int col = tensor * 1024 + head * 256 + ch0;
  const float* cw = (tensor == 0) ? cq : (tensor == 1) ? ck : cv;
  float w4[8][4];
#pragma unroll
  for (int e = 0; e < 8; ++e)
#pragma unroll
    for (int j = 0; j < 4; ++j) w4[e][j] = cw[(head * 256 + ch0 + e) * 4 + j];
  float h0[8], h1[8], h2[8];
#pragma unroll
  for (int e = 0; e < 8; ++e) { h0[e] = 0.f; h1[e] = 0.f; h2[e] = 0.f; }
  {
    if (l0 - 3 >= 0) {
      const short8 r = *(const short8*)&qkv[(((size_t)b << 12) + l0 - 3) * 3072 + col];
#pragma unroll
      for (int e = 0; e < 8; ++e) h0[e] = bf2f((unsigned short)r[e]);
    }
    if (l0 - 2 >= 0) {
      const short8 r = *(const short8*)&qkv[(((size_t)b << 12) + l0 - 2) * 3072 + col];
#pragma unroll
      for (int e = 0; e < 8; ++e) h1[e] = bf2f((unsigned short)r[e]);
    }
    if (l0 - 1 >= 0) {
      const short8 r = *(const short8*)&qkv[(((size_t)b << 12) + l0 - 1) * 3072 + col];
#pragma unroll
      for (int e = 0; e < 8; ++e) h2[e] = bf2f((unsigned short)r[e]);
    }
  }
  unsigned short* outp = (tensor == 0) ? qn : (tensor == 1) ? kn : vn;
  const size_t obase = (((size_t)(b * Hn + head)) << 12) * 256 + ch0;
#pragma unroll
  for (int i = 0; i < CLT; ++i) {
    const int l = l0 + i;
    const short8 r = *(const short8*)&qkv[(((size_t)b << 12) + l) * 3072 + col];
    float cur[8], a[8];
#pragma unroll
    for (int e = 0; e < 8; ++e) cur[e] = bf2f((unsigned short)r[e]);
    float ssq = 0.f;
#pragma unroll
    for (int e = 0; e < 8; ++e) {
      float s = w4[e][3] * cur[e];
      s = fmaf(w4[e][0], h0[e], s);
      s = fmaf(w4[e][1], h1[e], s);
      s = fmaf(w4[e][2], h2[e], s);
      const float y = s * sigmoidf_(s);
      a[e] = y;
      ssq = fmaf(y, y, ssq);
      h0[e] = h1[e]; h1[e] = h2[e]; h2[e] = cur[e];
    }
    float sc = 1.f;
    if (tensor < 2) {
#pragma unroll
      for (int m = 1; m <= 16; m <<= 1) ssq += __shfl_xor(ssq, m);
      sc = rsqrtf(ssq + 1e-6f);
    }
    short8 o;
#pragma unroll
    for (int e = 0; e < 8; ++e) o[e] = (short)f2bf(a[e] * sc);
    *(short8*)&outp[obase + (size_t)l * 256] = o;
  }
}

// ---------------------------------------------------------------------------
// Precomp v3 (round-16, passed).
// ---------------------------------------------------------------------------
__global__ __launch_bounds__(256, 2) void precomp_kernel(
    const unsigned short* __restrict__ q, const unsigned short* __restrict__ k,
    const unsigned short* __restrict__ v, const float* __restrict__ beta,
    unsigned short* __restrict__ wfrag, unsigned short* __restrict__ qfrag,
    unsigned short* __restrict__ ktfrag, unsigned short* __restrict__ afrag,
    float* __restrict__ u0frag) {
  const int blk = blockIdx.x;
  const int n = blk & 127, bh = blk >> 7;
  const size_t base = (((size_t)bh << 12) + (n << 5)) * 256;
  const size_t cid = (size_t)(bh * NCHn + n);
  __shared__ __align__(16) unsigned short ksb[32][264];
  __shared__ __align__(16) unsigned short qsb[32][264];
  __shared__ __align__(16) unsigned short vbb[32][264];
  __shared__ float Tm[32][33], Am[32][33], bet[32];
  __shared__ __align__(16) float attn_l[32][36];
  const int t = threadIdx.x;
  const int wid = t >> 6, lane = t & 63;
  const int fr = lane & 15, fg = lane >> 4;
  if (t < 32) bet[t] = beta[((size_t)bh << 12) + (n << 5) + t];
#pragma unroll
  for (int it = 0; it < 4; ++it) {
    const int idx = t + it * 256;
    const int r = idx >> 5, c8 = (idx & 31) << 3;
    const float bv = beta[((size_t)bh << 12) + (n << 5) + r];
    *(int4*)&qsb[r][c8] = *(const int4*)&q[base + r * 256 + c8];
    *(int4*)&ksb[r][c8] = *(const int4*)&k[base + r * 256 + c8];
    const int4 vv = *(const int4*)&v[base + r * 256 + c8];
    const unsigned vu[4] = {(unsigned)vv.x, (unsigned)vv.y, (unsigned)vv.z, (unsigned)vv.w};
    int4 ov;
    ov.x = cvt_pk_bf16(bf2f((unsigned short)(vu[0] & 0xffff)) * bv,
                       bf2f((unsigned short)(vu[0] >> 16)) * bv);
    ov.y = cvt_pk_bf16(bf2f((unsigned short)(vu[1] & 0xffff)) * bv,
                       bf2f((unsigned short)(vu[1] >> 16)) * bv);
    ov.z = cvt_pk_bf16(bf2f((unsigned short)(vu[2] & 0xffff)) * bv,
                       bf2f((unsigned short)(vu[2] >> 16)) * bv);
    ov.w = cvt_pk_bf16(bf2f((unsigned short)(vu[3] & 0xffff)) * bv,
                       bf2f((unsigned short)(vu[3] >> 16)) * bv);
    *(int4*)&vbb[r][c8] = ov;
  }
  __syncthreads();
  {
    const int ti = wid >> 1, tj = wid & 1;
    f32x4 G = (f32x4){0.f, 0.f, 0.f, 0.f};
    f32x4 At = (f32x4){0.f, 0.f, 0.f, 0.f};
#pragma unroll
    for (int kw = 0; kw < 8; ++kw) {
      const short8 krow = *(const short8*)&ksb[ti * 16 + fr][kw * 32 + fg * 8];
      const short8 kcol = *(const short8*)&ksb[tj * 16 + fr][kw * 32 + fg * 8];
      const short8 qrow = *(const short8*)&qsb[ti * 16 + fr][kw * 32 + fg * 8];
      G = __builtin_amdgcn_mfma_f32_16x16x32_bf16(krow, kcol, G, 0, 0, 0);
      At = __builtin_amdgcn_mfma_f32_16x16x32_bf16(qrow, kcol, At, 0, 0, 0);
    }
#pragma unroll
    for (int r_ = 0; r_ < 4; ++r_) {
      const int i = ti * 16 + fg * 4 + r_;
      const int j = tj * 16 + fr;
      Am[i][j] = bet[i] * G[r_];
      attn_l[i][j] = (j <= i) ? At[r_] : 0.f;
    }
  }
#pragma unroll
  for (int it = 0; it < 4; ++it) {
    const int u = it * 4 + wid;
    const int mi = u >> 3, kw = u & 7;
    *(int4*)&qfrag[cid * 8192 + u * 512 + lane * 8] =
        *(const int4*)&qsb[mi * 16 + fr][kw * 32 + fg * 8];
  }
#pragma unroll
  for (int it = 0; it < 4; ++it) {
    const int mi = it * 4 + wid;
    const int dk = mi * 16 + fr;
    unsigned short e[8];
#pragma unroll
    for (int j = 0; j < 8; ++j) e[j] = ksb[fg * 8 + j][dk];
    int4 o;
    o.x = e[0] | ((unsigned)e[1] << 16);
    o.y = e[2] | ((unsigned)e[3] << 16);
    o.z = e[4] | ((unsigned)e[5] << 16);
    o.w = e[6] | ((unsigned)e[7] << 16);
    *(int4*)&ktfrag[cid * 8192 + mi * 512 + lane * 8] = o;
  }
  __syncthreads();
  if (t >= 128) {
    const int mi = (t >> 6) - 2;
    const int c = mi * 16 + fr;
    const float4 a = *(const float4*)&attn_l[c][fg * 8];
    const float4 b2 = *(const float4*)&attn_l[c][fg * 8 + 4];
    int4 o;
    o.x = f2bf(a.x) | ((unsigned)f2bf(a.y) << 16);
    o.y = f2bf(a.z) | ((unsigned)f2bf(a.w) << 16);
    o.z = f2bf(b2.x) | ((unsigned)f2bf(b2.y) << 16);
    o.w = f2bf(b2.z) | ((unsigned)f2bf(b2.w) << 16);
    *(int4*)&afrag[cid * 1024 + mi * 512 + lane * 8] = o;
  }
  if (t < 32) {
    float Tcol[32];
    Tcol[0] = (t == 0) ? 1.f : 0.f;
#pragma unroll
    for (int i = 1; i < 32; ++i) {
      float s0 = 0.f, s1 = 0.f;
      int m = 0;
#pragma unroll
      for (; m + 2 <= i; m += 2) {
        s0 = fmaf(Am[i][m], Tcol[m], s0);
        s1 = fmaf(Am[i][m + 1], Tcol[m + 1], s1);
      }
      if (m < i) s0 = fmaf(Am[i][m], Tcol[m], s0);
      Tcol[i] = ((i == t) ? 1.f : 0.f) - s0 - s1;
    }
#pragma unroll
    for (int i = 0; i < 32; ++i) Tm[i][t] = Tcol[i];
  }
  __syncthreads();
  {
    float betr[8];
#pragma unroll
    for (int j = 0; j < 8; ++j) betr[j] = bet[fg * 8 + j];
    short8 Tf[2], Tbf[2];
#pragma unroll
    for (int mi = 0; mi < 2; ++mi) {
      float tv[8];
#pragma unroll
      for (int j = 0; j < 8; ++j) tv[j] = Tm[mi * 16 + fr][fg * 8 + j];
      int4 p, pb;
      p.x = cvt_pk_bf16(tv[0], tv[1]); p.y = cvt_pk_bf16(tv[2], tv[3]);
      p.z = cvt_pk_bf16(tv[4], tv[5]); p.w = cvt_pk_bf16(tv[6], tv[7]);
      pb.x = cvt_pk_bf16(tv[0] * betr[0], tv[1] * betr[1]);
      pb.y = cvt_pk_bf16(tv[2] * betr[2], tv[3] * betr[3]);
      pb.z = cvt_pk_bf16(tv[4] * betr[4], tv[5] * betr[5]);
      pb.w = cvt_pk_bf16(tv[6] * betr[6], tv[7] * betr[7]);
      Tf[mi] = pack_i4(p);
      Tbf[mi] = pack_i4(pb);
    }
    const f32x4 zero = (f32x4){0.f, 0.f, 0.f, 0.f};
#pragma unroll
    for (int tt = 0; tt < 4; ++tt) {
      const int tjc = wid * 4 + tt;
      unsigned short ev[8], ek[8];
#pragma unroll
      for (int j = 0; j < 8; ++j) {
        ev[j] = vbb[fg * 8 + j][tjc * 16 + fr];
        ek[j] = ksb[fg * 8 + j][tjc * 16 + fr];
      }
      int4 pv, pk;
      pv.x = ev[0] | ((unsigned)ev[1] << 16); pv.y = ev[2] | ((unsigned)ev[3] << 16);
      pv.z = ev[4] | ((unsigned)ev[5] << 16); pv.w = ev[6] | ((unsigned)ev[7] << 16);
      pk.x = ek[0] | ((unsigned)ek[1] << 16); pk.y = ek[2] | ((unsigned)ek[3] << 16);
      pk.z = ek[4] | ((unsigned)ek[5] << 16); pk.w = ek[6] | ((unsigned)ek[7] << 16);
      const short8 vbf = pack_i4(pv);
      const short8 kbf = pack_i4(pk);
#pragma unroll
      for (int mi = 0; mi < 2; ++mi) {
        const f32x4 U = __builtin_amdgcn_mfma_f32_16x16x32_bf16(Tf[mi], vbf, zero, 0, 0, 0);
        *(f32x4*)&u0frag[cid * 8192 + (tjc * 2 + mi) * 256 + lane * 4] = U;
        const f32x4 W = __builtin_amdgcn_mfma_f32_16x16x32_bf16(Tbf[mi], kbf, zero, 0, 0, 0);
#pragma unroll
        for (int r_ = 0; r_ < 4; ++r_)
          qsb[mi * 16 + fg * 4 + r_][tjc * 16 + fr] = f2bf(W[r_]);
      }
    }
  }
  __syncthreads();
#pragma unroll
  for (int it = 0; it < 4; ++it) {
    const int u = it * 4 + wid;
    const int mi = u >> 3, kw = u & 7;
    *(int4*)&wfrag[cid * 8192 + u * 512 + lane * 8] =
        *(const int4*)&qsb[mi * 16 + fr][kw * 32 + fg * 8];
  }
}

// ---------------------------------------------------------------------------
// Scan v7c: v7b with S-update MFMAs issued first after ub (critical path),
// o-work and prefetches after. Sync structure identical to v7b (passed).
// ---------------------------------------------------------------------------
__global__ __launch_bounds__(128, 1) void scan_mfma(
    const unsigned short* __restrict__ wfrag, const unsigned short* __restrict__ qfrag,
    const unsigned short* __restrict__ ktfrag, const unsigned short* __restrict__ afrag,
    const float* __restrict__ u0frag, unsigned short* __restrict__ dout) {
  const int bh = blockIdx.x & 7;
  const int dvs = blockIdx.x >> 3;
  const int tid = threadIdx.x;
  const int w = tid >> 6;
  const int lane = tid & 63;
  const int fr = lane & 15, fg = lane >> 4;
  const int swz = (fr & 7) << 4;
  __shared__ __align__(16) unsigned short St[2][2048];
  __shared__ __align__(16) unsigned short ut2[2][512];
  __shared__ __align__(16) float pux[2][2][2][256];
  __shared__ __align__(16) float pox[2][2][2][256];
  f32x4 S[8];
#pragma unroll
  for (int i = 0; i < 8; ++i) S[i] = (f32x4){0.f, 0.f, 0.f, 0.f};

  const unsigned short* wbase = wfrag + (size_t)(bh * NCHn) * 8192;
  const unsigned short* qbase = qfrag + (size_t)(bh * NCHn) * 8192;
  const unsigned short* kbase = ktfrag + (size_t)(bh * NCHn) * 8192;
  const unsigned short* abase = afrag + (size_t)(bh * NCHn) * 1024;
  const float* ubase = u0frag + (size_t)(bh * NCHn) * 8192 + dvs * 512;

  short8 wr[8], qr[8], ktr[8];
  short8 ar[2] = {};
  f32x4 u0r[2];
#pragma unroll
  for (int u8 = 0; u8 < 8; ++u8) {
    const int mi = u8 >> 2, kwp = u8 & 3;
    const int u = mi * 8 + 4 * w + kwp;
    wr[u8] = *(const short8*)&wbase[u * 512 + lane * 8];
    qr[u8] = *(const short8*)&qbase[u * 512 + lane * 8];
    ktr[u8] = *(const short8*)&kbase[(8 * w + u8) * 512 + lane * 8];
  }
#pragma unroll
  for (int u = 0; u < 2; ++u) u0r[u] = *(const f32x4*)&ubase[u * 256 + lane * 4];
  if (w == 0) {
#pragma unroll
    for (int u = 0; u < 2; ++u) ar[u] = *(const short8*)&abase[u * 512 + lane * 8];
  }

  for (int n = 0; n < NCHn; ++n) {
    const int np = (n + 1 < NCHn) ? (n + 1) : n;
    const int buf = n & 1;
#pragma unroll
    for (int mi = 0; mi < 8; ++mi) {
      const unsigned w0 = cvt_pk_bf16(S[mi][0], S[mi][1]);
      const unsigned w1 = cvt_pk_bf16(S[mi][2], S[mi][3]);
      const int a = (fr * 256 + mi * 32 + fg * 8) ^ swz;
      *(uint2*)((char*)&St[w][0] + a) = make_uint2(w0, w1);
    }
    short8 sb[4];
#pragma unroll
    for (int kwp = 0; kwp < 4; ++kwp) {
      const int a = (fr * 256 + kwp * 64 + fg * 16) ^ swz;
      sb[kwp] = *(const short8*)((const char*)&St[w][0] + a);
    }
    f32x4 up[2], oq[2];
    up[0] = up[1] = (f32x4){0.f, 0.f, 0.f, 0.f};
    oq[0] = oq[1] = (f32x4){0.f, 0.f, 0.f, 0.f};
#pragma unroll
    for (int kwp = 0; kwp < 4; ++kwp) {
#pragma unroll
      for (int mi = 0; mi < 2; ++mi) {
        up[mi] = __builtin_amdgcn_mfma_f32_16x16x32_bf16(wr[mi * 4 + kwp], sb[kwp], up[mi], 0, 0, 0);
        oq[mi] = __builtin_amdgcn_mfma_f32_16x16x32_bf16(qr[mi * 4 + kwp], sb[kwp], oq[mi], 0, 0, 0);
      }
    }
    {
      const unsigned short* wp = wbase + (size_t)np * 8192;
      const unsigned short* qp = qbase + (size_t)np * 8192;
#pragma unroll
      for (int u8 = 0; u8 < 8; ++u8) {
        const int mi = u8 >> 2, kwp = u8 & 3;
        const int u = mi * 8 + 4 * w + kwp;
        wr[u8] = *(const short8*)&wp[u * 512 + lane * 8];
        qr[u8] = *(const short8*)&qp[u * 512 + lane * 8];
      }
    }
#pragma unroll
    for (int mi = 0; mi < 2; ++mi) {
      *(f32x4*)&pux[w][buf][mi][lane * 4] = up[mi];
      *(f32x4*)&pox[w][buf][mi][lane * 4] = oq[mi];
    }
    asm volatile("s_waitcnt lgkmcnt(0)" ::: "memory");
    __builtin_amdgcn_s_barrier();
    __builtin_amdgcn_sched_barrier(0);
    f32x4 o_f[2];
#pragma unroll
    for (int mi = 0; mi < 2; ++mi) {
      const f32x4 puo = *(const f32x4*)&pux[w ^ 1][buf][mi][lane * 4];
      const f32x4 uu = u0r[mi] - up[mi] - puo;
      const unsigned a0 = cvt_pk_bf16(uu[0], uu[1]);
      const unsigned a1 = cvt_pk_bf16(uu[2], uu[3]);
      const int ad = (fr * 64 + mi * 32 + fg * 8) ^ swz;
      *(uint2*)((char*)&ut2[w][0] + ad) = make_uint2(a0, a1);
      o_f[mi] = oq[mi] + *(const f32x4*)&pox[w ^ 1][buf][mi][lane * 4];
    }
    asm volatile("s_waitcnt lgkmcnt(0)" ::: "memory");
    __builtin_amdgcn_sched_barrier(0);
    const short8 ub = *(const short8*)((const char*)&ut2[w][0] + ((fr * 64 + fg * 16) ^ swz));
    // S-update first: the only ub-consumer on the serial chain
#pragma unroll
    for (int mi = 0; mi < 8; ++mi)
      S[mi] = __builtin_amdgcn_mfma_f32_16x16x32_bf16(ktr[mi], ub, S[mi], 0, 0, 0);
    // o-work (off critical path)
    if (w == 0) {
#pragma unroll
      for (int mi = 0; mi < 2; ++mi)
        o_f[mi] = __builtin_amdgcn_mfma_f32_16x16x32_bf16(ar[mi], ub, o_f[mi], 0, 0, 0);
      const unsigned short* ap = abase + (size_t)np * 1024;
#pragma unroll
      for (int u = 0; u < 2; ++u) ar[u] = *(const short8*)&ap[u * 512 + lane * 8];
      const size_t cb = ((size_t)((bh << 12) + (n << 5))) * 256;
#pragma unroll
      for (int mi = 0; mi < 2; ++mi)
#pragma unroll
        for (int r = 0; r < 4; ++r)
          dout[cb + (size_t)(mi * 16 + fg * 4 + r) * 256 + dvs * 16 + fr] = f2bf(o_f[mi][r]);
    }
    // prefetches
    {
      const float* up_ = ubase + (size_t)np * 8192;
#pragma unroll
      for (int u = 0; u < 2; ++u) u0r[u] = *(const f32x4*)&up_[u * 256 + lane * 4];
      const unsigned short* kp = kbase + (size_t)np * 8192;
#pragma unroll
      for (int u8 = 0; u8 < 8; ++u8)
        ktr[u8] = *(const short8*)&kp[(8 * w + u8) * 512 + lane * 8];
    }
  }
}

// ---------------------------------------------------------------------------
// Mix v4 (round-16, passed).
// ---------------------------------------------------------------------------
#define MIX_LT 16
__global__ __launch_bounds__(256) void mix_kernel(
    const unsigned short* __restrict__ v, const unsigned short* __restrict__ delta,
    const float* __restrict__ wgl, const float* __restrict__ pmix,
    const float* __restrict__ firs, const float* __restrict__ firl,
    const float* __restrict__ rms_w, unsigned short* __restrict__ out) {
  const int wgid = ((int)blockIdx.x & 7) * 256 + ((int)blockIdx.x >> 3);
  const int b = wgid >> 10;
  const int h = (wgid >> 8) & 3;
  const int lt = wgid & 255;
  const int l0 = lt * MIX_LT;
  const int t = threadIdx.x;
  const int wv = t >> 6, lane = t & 63;
  const unsigned short* vcol = v + ((((size_t)(b * Hn + h)) << 12)) * 256 + t;
  const unsigned short* dcol = delta + ((((size_t)(b * Hn + h)) << 12)) * 256 + t;
  float fw[31], fs3[3];
#pragma unroll
  for (int j = 0; j < 31; ++j) fw[j] = firl[((h << 8) + t) * 31 + j];
#pragma unroll
  for (int j = 0; j < 3; ++j) fs3[j] = firs[((h << 8) + t) * 3 + j];
  const float rw = rms_w[t];
  float vbuf[46];
#pragma unroll
  for (int j = 0; j < 30; ++j) {
    const int ls = l0 - 30 + j;
    vbuf[j] = (ls >= 0) ? bf2f(vcol[(size_t)ls * 256]) : 0.f;
  }
#pragma unroll
  for (int i = 0; i < MIX_LT; ++i) vbuf[30 + i] = bf2f(vcol[(size_t)(l0 + i) * 256]);
  __shared__ float wred[MIX_LT * 4];
  float o[MIX_LT];
#pragma unroll
  for (int i = 0; i < MIX_LT; ++i) {
    const int l = l0 + i;
    const float vnew = vbuf[30 + i];
    float lo = fw[30] * vnew;
#pragma unroll
    for (int j = 0; j < 30; ++j) lo = fmaf(fw[j], vbuf[i + j], lo);
    float sh = fs3[2] * vnew;
    sh = fmaf(fs3[1], vbuf[i + 29], sh);
    sh = fmaf(fs3[0], vbuf[i + 28], sh);
    const int row = (b << 12) + l;
    const float p0 = pmix[row * 12 + h * 3 + 0];
    const float p1 = pmix[row * 12 + h * 3 + 1];
    const float p2 = pmix[row * 12 + h * 3 + 2];
    const float wg = wgl[row * 4 + h];
    const float mixv = p0 * vnew + p1 * sh + p2 * lo;
    const float oo = wg * bf2f(dcol[(size_t)l * 256]) + (1.f - wg) * mixv;
    o[i] = oo;
    float ss = oo * oo;
#pragma unroll
    for (int m = 1; m < 64; m <<= 1) ss += __shfl_xor(ss, m);
    if (lane == 0) wred[i * 4 + wv] = ss;
  }
  __syncthreads();
#pragma unroll
  for (int i = 0; i < MIX_LT; ++i) {
    const float sum = wred[i * 4] + wred[i * 4 + 1] + wred[i * 4 + 2] + wred[i * 4 + 3];
    const float sc = rsqrtf(sum * (1.f / 256.f) + 1e-5f);
    const int l = l0 + i;
    out[(size_t)((b << 12) + l) * 1024 + (h << 8) + t] = f2bf(o[i] * sc * rw);
  }
}

// ---------------------------------------------------------------------------
extern "C" void kernel_launch(void* const* d_in, const int* in_sizes, int n_in,
                              void* d_out, int out_size, void* d_ws, size_t ws_size,
                              hipStream_t stream) {
  const float* x = (const float*)d_in[0];
  const float* Wq = (const float*)d_in[1];
  const float* Wk = (const float*)d_in[2];
  const float* Wv = (const float*)d_in[3];
  const float* cq = (const float*)d_in[4];
  const float* ck = (const float*)d_in[5];
  const float* cv = (const float*)d_in[6];
  const float* Wb = (const float*)d_in[7];
  const float* firs = (const float*)d_in[8];
  const float* firl = (const float*)d_in[9];
  const float* Wg = (const float*)d_in[10];
  const float* bg = (const float*)d_in[11];
  const float* Wl = (const float*)d_in[12];
  const float* bl = (const float*)d_in[13];
  const float* ltemp = (const float*)d_in[14];
  const float* rmsw = (const float*)d_in[15];
  const float* Wo = (const float*)d_in[16];

  float* ws = (float*)d_ws;
  const size_t NE = (size_t)Bn * Ln * 1024;  // 8.39M
  unsigned short* qkvbf = (unsigned short*)ws;
  unsigned short* wfrag = (unsigned short*)ws;
  unsigned short* qfrag = wfrag + 8388608;
  unsigned short* ktfrag = (unsigned short*)(ws + NE);
  unsigned short* afrag = ktfrag + 8388608;
  float* u0frag = ws + 2 * NE;
  unsigned short* xb = (unsigned short*)(ws + 3 * NE);
  unsigned short* normed_bf = xb;
  unsigned short* Wqt = xb + NE;
  unsigned short* Wkt = Wqt + 1048576;
  unsigned short* Wvt = Wkt + 1048576;
  unsigned short* qn_bf = (unsigned short*)(ws + 4 * NE);
  unsigned short* kn_bf = qn_bf + NE;
  unsigned short* vn_bf = (unsigned short*)(ws + 5 * NE);
  unsigned short* dout_bf = vn_bf + NE;
  float* beta = ws + 6 * NE;
  float* wgl = beta + (size_t)Bn * Hn * Ln;
  float* pmix = wgl + (size_t)Bn * Ln * Hn;
  unsigned short* Wot = (unsigned short*)(pmix + (size_t)Bn * Ln * Hn * 3);

  wt_all_kernel<<<dim3(32, 32, 4), 256, 0, stream>>>(Wq, Wk, Wv, Wo,
                                                     Wqt, Wkt, Wvt, Wot);
  gates_kernel<<<Bn * Ln / 4, 256, 0, stream>>>(x, Wb, Wg, bg, Wl, bl, ltemp,
                                                beta, wgl, pmix, xb);
  // merged q/k/v projection: 1536 blocks (divisible by 8 for XCD swizzle)
  gemm_bf16<1><<<1536, 256, 0, stream>>>(xb, Wqt, qkvbf, Bn * Ln, 3072, 1024);
  conv_fused_kernel<<<Bn * (Ln / CLT), 384, 0, stream>>>(qkvbf, cq, ck, cv,
                                                         qn_bf, kn_bf, vn_bf);
  precomp_kernel<<<Bn * Hn * NCHn, 256, 0, stream>>>(qn_bf, kn_bf, vn_bf, beta,
                                                     wfrag, qfrag, ktfrag, afrag,
                                                     u0frag);
  scan_mfma<<<128, 128, 0, stream>>>(wfrag, qfrag, ktfrag, afrag, u0frag, dout_bf);
  mix_kernel<<<Bn * Hn * (Ln / MIX_LT), 256, 0, stream>>>(
      vn_bf, dout_bf, wgl, pmix, firs, firl, rmsw, normed_bf);
  gemm_bf16<0><<<512, 256, 0, stream>>>(normed_bf, Wot, (float*)d_out,
                                        Bn * Ln, 1024, 1024);
}